// Round 1
// baseline (1835.718 us; speedup 1.0000x reference)
//
#include <hip/hip_runtime.h>

namespace {

constexpr int B = 4;
constexpr int N = 8192;
constexpr int D = 16;
constexpr int R = 32;
constexpr int H = 64;
constexpr int E = 262144;   // 2^18

__global__ __launch_bounds__(256) void zero_kernel(float4* __restrict__ p, int n4) {
    int i = blockIdx.x * 256 + threadIdx.x;
    if (i < n4) p[i] = float4{0.f, 0.f, 0.f, 0.f};
}

// One thread per (b, e). Weights in LDS, read via uniform-address float4
// (broadcast ds_read_b128, no bank conflicts). Layer1 and layer2 fused per
// 4-wide h-slice so h[64] never lives as a register array.
__global__ __launch_bounds__(256) void edge_kernel(
    const float* __restrict__ particles,
    const int*   __restrict__ senders,
    const int*   __restrict__ receivers,
    const float* __restrict__ W1, const float* __restrict__ b1,
    const float* __restrict__ W2, const float* __restrict__ b2,
    float* __restrict__ rel)
{
    __shared__ __align__(16) float sW1[2 * D * H];  // 32 x 64
    __shared__ __align__(16) float sW2[H * R];      // 64 x 32
    __shared__ __align__(16) float sb1[H];
    __shared__ __align__(16) float sb2[R];

    for (int i = threadIdx.x; i < 2 * D * H; i += 256) sW1[i] = W1[i];
    for (int i = threadIdx.x; i < H * R;     i += 256) sW2[i] = W2[i];
    if (threadIdx.x < H) sb1[threadIdx.x] = b1[threadIdx.x];
    if (threadIdx.x < R) sb2[threadIdx.x] = b2[threadIdx.x];
    __syncthreads();

    const int idx = blockIdx.x * 256 + threadIdx.x;  // [0, B*E)
    const int b = idx >> 18;                          // E = 2^18
    const int e = idx & (E - 1);
    const int s = senders[e];
    const int r = receivers[e];

    float ein[2 * D];
    {
        const float4* ps = reinterpret_cast<const float4*>(particles + ((size_t)b * N + s) * D);
        const float4* pr = reinterpret_cast<const float4*>(particles + ((size_t)b * N + r) * D);
        #pragma unroll
        for (int q = 0; q < 4; ++q) {
            float4 v = ps[q];
            ein[4*q+0] = v.x; ein[4*q+1] = v.y; ein[4*q+2] = v.z; ein[4*q+3] = v.w;
        }
        #pragma unroll
        for (int q = 0; q < 4; ++q) {
            float4 v = pr[q];
            ein[D+4*q+0] = v.x; ein[D+4*q+1] = v.y; ein[D+4*q+2] = v.z; ein[D+4*q+3] = v.w;
        }
    }

    float rf[R];
    #pragma unroll
    for (int q = 0; q < R; ++q) rf[q] = sb2[q];

    for (int j4 = 0; j4 < H / 4; ++j4) {
        float4 hacc = *reinterpret_cast<const float4*>(sb1 + 4 * j4);
        const float* w1c = sW1 + 4 * j4;
        #pragma unroll
        for (int k = 0; k < 2 * D; ++k) {
            float4 w = *reinterpret_cast<const float4*>(w1c + k * H);
            hacc.x = fmaf(ein[k], w.x, hacc.x);
            hacc.y = fmaf(ein[k], w.y, hacc.y);
            hacc.z = fmaf(ein[k], w.z, hacc.z);
            hacc.w = fmaf(ein[k], w.w, hacc.w);
        }
        hacc.x = fmaxf(hacc.x, 0.f);
        hacc.y = fmaxf(hacc.y, 0.f);
        hacc.z = fmaxf(hacc.z, 0.f);
        hacc.w = fmaxf(hacc.w, 0.f);

        const float* w2r = sW2 + (4 * j4) * R;
        #pragma unroll
        for (int q = 0; q < 4; ++q) {
            const float hq = (q == 0) ? hacc.x : (q == 1) ? hacc.y : (q == 2) ? hacc.z : hacc.w;
            #pragma unroll
            for (int r4 = 0; r4 < R / 4; ++r4) {
                float4 w = *reinterpret_cast<const float4*>(w2r + q * R + 4 * r4);
                rf[4*r4+0] = fmaf(hq, w.x, rf[4*r4+0]);
                rf[4*r4+1] = fmaf(hq, w.y, rf[4*r4+1]);
                rf[4*r4+2] = fmaf(hq, w.z, rf[4*r4+2]);
                rf[4*r4+3] = fmaf(hq, w.w, rf[4*r4+3]);
            }
        }
    }

    float* dst = rel + ((size_t)b * N + r) * R;
    #pragma unroll
    for (int q = 0; q < R; ++q) {
        atomicAdd(dst + q, fmaxf(rf[q], 0.f));
    }
}

// One thread per (b, n). Same fused structure; residual add on store.
__global__ __launch_bounds__(256) void node_kernel(
    const float* __restrict__ particles,
    const float* __restrict__ rel,
    const float* __restrict__ W3, const float* __restrict__ b3,
    const float* __restrict__ W4, const float* __restrict__ b4,
    float* __restrict__ out)
{
    __shared__ __align__(16) float sW3[(D + R) * H];  // 48 x 64
    __shared__ __align__(16) float sW4[H * D];        // 64 x 16
    __shared__ __align__(16) float sb3[H];
    __shared__ __align__(16) float sb4[D];

    for (int i = threadIdx.x; i < (D + R) * H; i += 256) sW3[i] = W3[i];
    for (int i = threadIdx.x; i < H * D;       i += 256) sW4[i] = W4[i];
    if (threadIdx.x < H) sb3[threadIdx.x] = b3[threadIdx.x];
    if (threadIdx.x < D) sb4[threadIdx.x] = b4[threadIdx.x];
    __syncthreads();

    const int idx = blockIdx.x * 256 + threadIdx.x;  // [0, B*N)

    float in[D + R];
    {
        const float4* pp = reinterpret_cast<const float4*>(particles + (size_t)idx * D);
        #pragma unroll
        for (int q = 0; q < 4; ++q) {
            float4 v = pp[q];
            in[4*q+0] = v.x; in[4*q+1] = v.y; in[4*q+2] = v.z; in[4*q+3] = v.w;
        }
        const float4* pr = reinterpret_cast<const float4*>(rel + (size_t)idx * R);
        #pragma unroll
        for (int q = 0; q < 8; ++q) {
            float4 v = pr[q];
            in[D+4*q+0] = v.x; in[D+4*q+1] = v.y; in[D+4*q+2] = v.z; in[D+4*q+3] = v.w;
        }
    }

    float dl[D];
    #pragma unroll
    for (int q = 0; q < D; ++q) dl[q] = sb4[q];

    for (int j4 = 0; j4 < H / 4; ++j4) {
        float4 hacc = *reinterpret_cast<const float4*>(sb3 + 4 * j4);
        const float* w3c = sW3 + 4 * j4;
        #pragma unroll
        for (int k = 0; k < D + R; ++k) {
            float4 w = *reinterpret_cast<const float4*>(w3c + k * H);
            hacc.x = fmaf(in[k], w.x, hacc.x);
            hacc.y = fmaf(in[k], w.y, hacc.y);
            hacc.z = fmaf(in[k], w.z, hacc.z);
            hacc.w = fmaf(in[k], w.w, hacc.w);
        }
        hacc.x = fmaxf(hacc.x, 0.f);
        hacc.y = fmaxf(hacc.y, 0.f);
        hacc.z = fmaxf(hacc.z, 0.f);
        hacc.w = fmaxf(hacc.w, 0.f);

        const float* w4r = sW4 + (4 * j4) * D;
        #pragma unroll
        for (int q = 0; q < 4; ++q) {
            const float hq = (q == 0) ? hacc.x : (q == 1) ? hacc.y : (q == 2) ? hacc.z : hacc.w;
            #pragma unroll
            for (int d4 = 0; d4 < D / 4; ++d4) {
                float4 w = *reinterpret_cast<const float4*>(w4r + q * D + 4 * d4);
                dl[4*d4+0] = fmaf(hq, w.x, dl[4*d4+0]);
                dl[4*d4+1] = fmaf(hq, w.y, dl[4*d4+1]);
                dl[4*d4+2] = fmaf(hq, w.z, dl[4*d4+2]);
                dl[4*d4+3] = fmaf(hq, w.w, dl[4*d4+3]);
            }
        }
    }

    float4* po = reinterpret_cast<float4*>(out + (size_t)idx * D);
    #pragma unroll
    for (int q = 0; q < 4; ++q) {
        float4 v;
        v.x = in[4*q+0] + dl[4*q+0];
        v.y = in[4*q+1] + dl[4*q+1];
        v.z = in[4*q+2] + dl[4*q+2];
        v.w = in[4*q+3] + dl[4*q+3];
        po[q] = v;
    }
}

}  // namespace

extern "C" void kernel_launch(void* const* d_in, const int* in_sizes, int n_in,
                              void* d_out, int out_size, void* d_ws, size_t ws_size,
                              hipStream_t stream) {
    const float* particles = (const float*)d_in[0];
    const int*   senders   = (const int*)d_in[1];
    const int*   receivers = (const int*)d_in[2];
    const float* W1 = (const float*)d_in[3];
    const float* b1 = (const float*)d_in[4];
    const float* W2 = (const float*)d_in[5];
    const float* b2 = (const float*)d_in[6];
    const float* W3 = (const float*)d_in[7];
    const float* b3 = (const float*)d_in[8];
    const float* W4 = (const float*)d_in[9];
    const float* b4 = (const float*)d_in[10];

    float* out = (float*)d_out;
    float* rel = (float*)d_ws;   // B*N*R floats = 4 MiB accumulator

    const int n4 = B * N * R / 4;  // 262144 float4s
    zero_kernel<<<(n4 + 255) / 256, 256, 0, stream>>>((float4*)rel, n4);

    edge_kernel<<<(B * E) / 256, 256, 0, stream>>>(
        particles, senders, receivers, W1, b1, W2, b2, rel);

    node_kernel<<<(B * N) / 256, 256, 0, stream>>>(
        particles, rel, W3, b3, W4, b4, out);
}

// Round 2
// 338.132 us; speedup vs baseline: 5.4290x; 5.4290x over previous
//
#include <hip/hip_runtime.h>

namespace {

constexpr int B = 4;
constexpr int N = 8192;     // 2^13
constexpr int D = 16;
constexpr int R = 32;
constexpr int H = 64;
constexpr int E = 262144;   // 2^18

__device__ __forceinline__ float4 ld4(const float* p) {
    return *reinterpret_cast<const float4*>(p);
}

// Edge MLP: relu(relu([send,recv] @ W1 + b1) @ W2 + b2) -> rf[32].
// Weights read from global with wave-uniform addresses -> scalar s_load,
// v_fmac with SGPR operand. No LDS.
__device__ __forceinline__ void edge_mlp(
    const float* __restrict__ particles, int b, int s, int r,
    const float* __restrict__ W1, const float* __restrict__ b1,
    const float* __restrict__ W2, const float* __restrict__ b2,
    float rf[R])
{
    float ein[2 * D];
    {
        const float4* ps = reinterpret_cast<const float4*>(particles + ((size_t)b * N + s) * D);
        const float4* pr = reinterpret_cast<const float4*>(particles + ((size_t)b * N + r) * D);
        #pragma unroll
        for (int q = 0; q < 4; ++q) {
            float4 v = ps[q];
            ein[4*q+0] = v.x; ein[4*q+1] = v.y; ein[4*q+2] = v.z; ein[4*q+3] = v.w;
        }
        #pragma unroll
        for (int q = 0; q < 4; ++q) {
            float4 v = pr[q];
            ein[D+4*q+0] = v.x; ein[D+4*q+1] = v.y; ein[D+4*q+2] = v.z; ein[D+4*q+3] = v.w;
        }
    }

    #pragma unroll
    for (int q = 0; q < R; ++q) rf[q] = b2[q];

    for (int j4 = 0; j4 < H / 4; ++j4) {
        float4 hacc = ld4(b1 + 4 * j4);
        #pragma unroll
        for (int k = 0; k < 2 * D; ++k) {
            float4 w = ld4(W1 + k * H + 4 * j4);
            hacc.x = fmaf(ein[k], w.x, hacc.x);
            hacc.y = fmaf(ein[k], w.y, hacc.y);
            hacc.z = fmaf(ein[k], w.z, hacc.z);
            hacc.w = fmaf(ein[k], w.w, hacc.w);
        }
        hacc.x = fmaxf(hacc.x, 0.f);
        hacc.y = fmaxf(hacc.y, 0.f);
        hacc.z = fmaxf(hacc.z, 0.f);
        hacc.w = fmaxf(hacc.w, 0.f);

        #pragma unroll
        for (int q = 0; q < 4; ++q) {
            const float hq = (q == 0) ? hacc.x : (q == 1) ? hacc.y : (q == 2) ? hacc.z : hacc.w;
            #pragma unroll
            for (int r4 = 0; r4 < R / 4; ++r4) {
                float4 w = ld4(W2 + (4 * j4 + q) * R + 4 * r4);
                rf[4*r4+0] = fmaf(hq, w.x, rf[4*r4+0]);
                rf[4*r4+1] = fmaf(hq, w.y, rf[4*r4+1]);
                rf[4*r4+2] = fmaf(hq, w.z, rf[4*r4+2]);
                rf[4*r4+3] = fmaf(hq, w.w, rf[4*r4+3]);
            }
        }
    }
    // final relu
    #pragma unroll
    for (int q = 0; q < R; ++q) rf[q] = fmaxf(rf[q], 0.f);
}

// ---------- sort pipeline ----------

__global__ __launch_bounds__(256) void hist_kernel(
    const int* __restrict__ receivers, int* __restrict__ cnt)
{
    int e = blockIdx.x * 256 + threadIdx.x;
    if (e < E) atomicAdd(cnt + receivers[e], 1);
}

// single block, 1024 threads, exclusive scan of 8192 bins
__global__ __launch_bounds__(1024) void scan_kernel(
    const int* __restrict__ cnt, int* __restrict__ start, int* __restrict__ pos)
{
    __shared__ int part[1024];
    const int t = threadIdx.x;
    int local[8];
    int s = 0;
    #pragma unroll
    for (int i = 0; i < 8; ++i) { local[i] = cnt[t * 8 + i]; s += local[i]; }
    part[t] = s;
    __syncthreads();
    for (int off = 1; off < 1024; off <<= 1) {
        int v = (t >= off) ? part[t - off] : 0;
        __syncthreads();
        part[t] += v;
        __syncthreads();
    }
    int base = (t == 0) ? 0 : part[t - 1];
    #pragma unroll
    for (int i = 0; i < 8; ++i) {
        start[t * 8 + i] = base;
        pos[t * 8 + i] = base;
        base += local[i];
    }
    if (t == 1023) start[N] = base;   // == E
}

__global__ __launch_bounds__(256) void scatter_kernel(
    const int* __restrict__ receivers, int* __restrict__ pos, int* __restrict__ order)
{
    int e = blockIdx.x * 256 + threadIdx.x;
    if (e < E) {
        int p = atomicAdd(pos + receivers[e], 1);
        order[p] = e;
    }
}

// ---------- fast path: dense feat in sorted order ----------

__global__ __launch_bounds__(256) void edge_feat_kernel(
    const float* __restrict__ particles,
    const int*   __restrict__ senders,
    const int*   __restrict__ receivers,
    const int*   __restrict__ order,
    const float* __restrict__ W1, const float* __restrict__ b1,
    const float* __restrict__ W2, const float* __restrict__ b2,
    float* __restrict__ feat)
{
    const int idx = blockIdx.x * 256 + threadIdx.x;   // [0, B*E)
    const int b = idx >> 18;                           // E = 2^18
    const int p = idx & (E - 1);
    const int e = order[p];
    const int s = senders[e];
    const int r = receivers[e];

    float rf[R];
    edge_mlp(particles, b, s, r, W1, b1, W2, b2, rf);

    float4* dst = reinterpret_cast<float4*>(feat + ((size_t)b * E + p) * R);
    #pragma unroll
    for (int q = 0; q < R / 4; ++q) {
        dst[q] = float4{rf[4*q+0], rf[4*q+1], rf[4*q+2], rf[4*q+3]};
    }
}

// one wave per (b, n): sum the contiguous sorted segment
__global__ __launch_bounds__(256) void aggregate_kernel(
    const float* __restrict__ feat, const int* __restrict__ start,
    float* __restrict__ rel)
{
    const int wid = blockIdx.x * 4 + (threadIdx.x >> 6);  // [0, B*N)
    const int lane = threadIdx.x & 63;
    const int b = wid >> 13;           // N = 2^13
    const int n = wid & (N - 1);
    const int f = lane & 31;
    const int hh = lane >> 5;
    const int s0 = start[n];
    const int s1 = start[n + 1];
    float acc = 0.f;
    for (int i = s0 + hh; i < s1; i += 2)
        acc += feat[((size_t)b * E + i) * R + f];
    acc += __shfl_down(acc, 32, 64);
    if (lane < 32) rel[(size_t)wid * R + f] = acc;
}

// ---------- fallback path (atomics, proven correct in R1) ----------

__global__ __launch_bounds__(256) void edge_atomic_kernel(
    const float* __restrict__ particles,
    const int*   __restrict__ senders,
    const int*   __restrict__ receivers,
    const float* __restrict__ W1, const float* __restrict__ b1,
    const float* __restrict__ W2, const float* __restrict__ b2,
    float* __restrict__ rel)
{
    const int idx = blockIdx.x * 256 + threadIdx.x;
    const int b = idx >> 18;
    const int e = idx & (E - 1);
    const int s = senders[e];
    const int r = receivers[e];

    float rf[R];
    edge_mlp(particles, b, s, r, W1, b1, W2, b2, rf);

    float* dst = rel + ((size_t)b * N + r) * R;
    #pragma unroll
    for (int q = 0; q < R; ++q) atomicAdd(dst + q, rf[q]);
}

// ---------- node MLP (scalar weights, residual) ----------

__global__ __launch_bounds__(256) void node_kernel(
    const float* __restrict__ particles,
    const float* __restrict__ rel,
    const float* __restrict__ W3, const float* __restrict__ b3,
    const float* __restrict__ W4, const float* __restrict__ b4,
    float* __restrict__ out)
{
    const int idx = blockIdx.x * 256 + threadIdx.x;  // [0, B*N)

    float in[D + R];
    {
        const float4* pp = reinterpret_cast<const float4*>(particles + (size_t)idx * D);
        #pragma unroll
        for (int q = 0; q < 4; ++q) {
            float4 v = pp[q];
            in[4*q+0] = v.x; in[4*q+1] = v.y; in[4*q+2] = v.z; in[4*q+3] = v.w;
        }
        const float4* pr = reinterpret_cast<const float4*>(rel + (size_t)idx * R);
        #pragma unroll
        for (int q = 0; q < 8; ++q) {
            float4 v = pr[q];
            in[D+4*q+0] = v.x; in[D+4*q+1] = v.y; in[D+4*q+2] = v.z; in[D+4*q+3] = v.w;
        }
    }

    float dl[D];
    #pragma unroll
    for (int q = 0; q < D; ++q) dl[q] = b4[q];

    for (int j4 = 0; j4 < H / 4; ++j4) {
        float4 hacc = ld4(b3 + 4 * j4);
        #pragma unroll
        for (int k = 0; k < D + R; ++k) {
            float4 w = ld4(W3 + k * H + 4 * j4);
            hacc.x = fmaf(in[k], w.x, hacc.x);
            hacc.y = fmaf(in[k], w.y, hacc.y);
            hacc.z = fmaf(in[k], w.z, hacc.z);
            hacc.w = fmaf(in[k], w.w, hacc.w);
        }
        hacc.x = fmaxf(hacc.x, 0.f);
        hacc.y = fmaxf(hacc.y, 0.f);
        hacc.z = fmaxf(hacc.z, 0.f);
        hacc.w = fmaxf(hacc.w, 0.f);

        #pragma unroll
        for (int q = 0; q < 4; ++q) {
            const float hq = (q == 0) ? hacc.x : (q == 1) ? hacc.y : (q == 2) ? hacc.z : hacc.w;
            #pragma unroll
            for (int d4 = 0; d4 < D / 4; ++d4) {
                float4 w = ld4(W4 + (4 * j4 + q) * D + 4 * d4);
                dl[4*d4+0] = fmaf(hq, w.x, dl[4*d4+0]);
                dl[4*d4+1] = fmaf(hq, w.y, dl[4*d4+1]);
                dl[4*d4+2] = fmaf(hq, w.z, dl[4*d4+2]);
                dl[4*d4+3] = fmaf(hq, w.w, dl[4*d4+3]);
            }
        }
    }

    float4* po = reinterpret_cast<float4*>(out + (size_t)idx * D);
    #pragma unroll
    for (int q = 0; q < 4; ++q) {
        po[q] = float4{in[4*q+0] + dl[4*q+0], in[4*q+1] + dl[4*q+1],
                       in[4*q+2] + dl[4*q+2], in[4*q+3] + dl[4*q+3]};
    }
}

}  // namespace

extern "C" void kernel_launch(void* const* d_in, const int* in_sizes, int n_in,
                              void* d_out, int out_size, void* d_ws, size_t ws_size,
                              hipStream_t stream) {
    const float* particles = (const float*)d_in[0];
    const int*   senders   = (const int*)d_in[1];
    const int*   receivers = (const int*)d_in[2];
    const float* W1 = (const float*)d_in[3];
    const float* b1 = (const float*)d_in[4];
    const float* W2 = (const float*)d_in[5];
    const float* b2 = (const float*)d_in[6];
    const float* W3 = (const float*)d_in[7];
    const float* b3 = (const float*)d_in[8];
    const float* W4 = (const float*)d_in[9];
    const float* b4 = (const float*)d_in[10];
    float* out = (float*)d_out;

    // workspace layout (256-B aligned slices)
    char* ws = (char*)d_ws;
    size_t off = 0;
    auto take = [&](size_t bytes) -> char* {
        char* p = ws + off;
        off = (off + bytes + 255) & ~(size_t)255;
        return p;
    };
    int*   cnt   = (int*)  take((size_t)N * 4);
    int*   pos   = (int*)  take((size_t)N * 4);
    int*   start = (int*)  take((size_t)(N + 1) * 4);
    int*   order = (int*)  take((size_t)E * 4);
    float* rel   = (float*)take((size_t)B * N * R * 4);
    float* feat  = (float*)take((size_t)B * E * R * 4);
    const bool fast = (off <= ws_size);

    if (fast) {
        hipMemsetAsync(cnt, 0, (size_t)N * 4, stream);
        hist_kernel<<<E / 256, 256, 0, stream>>>(receivers, cnt);
        scan_kernel<<<1, 1024, 0, stream>>>(cnt, start, pos);
        scatter_kernel<<<E / 256, 256, 0, stream>>>(receivers, pos, order);
        edge_feat_kernel<<<(B * E) / 256, 256, 0, stream>>>(
            particles, senders, receivers, order, W1, b1, W2, b2, feat);
        aggregate_kernel<<<(B * N) / 4, 256, 0, stream>>>(feat, start, rel);
        node_kernel<<<(B * N) / 256, 256, 0, stream>>>(
            particles, rel, W3, b3, W4, b4, out);
    } else {
        float* rel0 = (float*)d_ws;
        hipMemsetAsync(rel0, 0, (size_t)B * N * R * 4, stream);
        edge_atomic_kernel<<<(B * E) / 256, 256, 0, stream>>>(
            particles, senders, receivers, W1, b1, W2, b2, rel0);
        node_kernel<<<(B * N) / 256, 256, 0, stream>>>(
            particles, rel0, W3, b3, W4, b4, out);
    }
}

// Round 3
// 298.044 us; speedup vs baseline: 6.1592x; 1.1345x over previous
//
#include <hip/hip_runtime.h>

namespace {

constexpr int B = 4;
constexpr int N = 8192;     // 2^13
constexpr int D = 16;
constexpr int R = 32;
constexpr int H = 64;
constexpr int E = 262144;   // 2^18

__device__ __forceinline__ float4 ld4(const float* p) {
    return *reinterpret_cast<const float4*>(p);
}
__device__ __forceinline__ float4 fma4(float a, float4 w, float4 c) {
    return float4{fmaf(a, w.x, c.x), fmaf(a, w.y, c.y),
                  fmaf(a, w.z, c.z), fmaf(a, w.w, c.w)};
}
__device__ __forceinline__ float4 relu4(float4 v) {
    return float4{fmaxf(v.x, 0.f), fmaxf(v.y, 0.f), fmaxf(v.z, 0.f), fmaxf(v.w, 0.f)};
}

// ---------- sort pipeline ----------

__global__ __launch_bounds__(256) void hist_kernel(
    const int* __restrict__ receivers, int* __restrict__ cnt)
{
    int e = blockIdx.x * 256 + threadIdx.x;
    if (e < E) atomicAdd(cnt + receivers[e], 1);
}

// single block, 1024 threads, exclusive scan of 8192 bins -> pos
__global__ __launch_bounds__(1024) void scan_kernel(
    const int* __restrict__ cnt, int* __restrict__ pos)
{
    __shared__ int part[1024];
    const int t = threadIdx.x;
    int local[8];
    int s = 0;
    #pragma unroll
    for (int i = 0; i < 8; ++i) { local[i] = cnt[t * 8 + i]; s += local[i]; }
    part[t] = s;
    __syncthreads();
    for (int off = 1; off < 1024; off <<= 1) {
        int v = (t >= off) ? part[t - off] : 0;
        __syncthreads();
        part[t] += v;
        __syncthreads();
    }
    int base = (t == 0) ? 0 : part[t - 1];
    #pragma unroll
    for (int i = 0; i < 8; ++i) {
        pos[t * 8 + i] = base;
        base += local[i];
    }
}

// also materialize sorted sender/receiver so the hot kernel reads coalesced
__global__ __launch_bounds__(256) void scatter_kernel(
    const int* __restrict__ senders, const int* __restrict__ receivers,
    int* __restrict__ pos, int* __restrict__ ssorted, int* __restrict__ rsorted)
{
    int e = blockIdx.x * 256 + threadIdx.x;
    if (e < E) {
        int r = receivers[e];
        int p = atomicAdd(pos + r, 1);
        ssorted[p] = senders[e];
        rsorted[p] = r;
    }
}

// ---------- fused edge MLP + segmented reduction ----------
// Block = 256 consecutive sorted positions within one batch b.
// Phase 1: per-thread edge MLP entirely in float4 registers.
// Phase 2: stage rf transposed in LDS (lds[f*257+p], conflict-free),
//          8 groups of 32 lanes segment-reduce their 32-position chunk,
//          one atomicAdd per (chunk, segment, feature).
__global__ __launch_bounds__(256, 2) void edge_fused_kernel(
    const float* __restrict__ particles,
    const int*   __restrict__ ssorted,
    const int*   __restrict__ rsorted,
    const float* __restrict__ W1, const float* __restrict__ b1,
    const float* __restrict__ W2, const float* __restrict__ b2,
    float* __restrict__ rel)
{
    __shared__ float lds[R * 257];   // [f][p] padded: bank = (f+p)%32
    __shared__ int   rs[256];

    const int tid = threadIdx.x;
    const int idx = blockIdx.x * 256 + tid;   // [0, B*E)
    const int b = idx >> 18;                   // E = 2^18
    const int p = idx & (E - 1);
    const int s = ssorted[p];
    const int r = rsorted[p];
    rs[tid] = r;

    // edge input [send(16) | recv(16)] as 8 float4 registers
    float4 ein4[8];
    {
        const float4* ps = reinterpret_cast<const float4*>(particles + ((size_t)b * N + s) * D);
        const float4* pr = reinterpret_cast<const float4*>(particles + ((size_t)b * N + r) * D);
        #pragma unroll
        for (int q = 0; q < 4; ++q) ein4[q] = ps[q];
        #pragma unroll
        for (int q = 0; q < 4; ++q) ein4[4 + q] = pr[q];
    }

    float4 rf4[8];
    #pragma unroll
    for (int q = 0; q < 8; ++q) rf4[q] = ld4(b2 + 4 * q);

    for (int j4 = 0; j4 < H / 4; ++j4) {
        float4 h = ld4(b1 + 4 * j4);
        const float* w1c = W1 + 4 * j4;
        #pragma unroll
        for (int kv = 0; kv < 8; ++kv) {
            const float4 ev = ein4[kv];
            h = fma4(ev.x, ld4(w1c + (4 * kv + 0) * H), h);
            h = fma4(ev.y, ld4(w1c + (4 * kv + 1) * H), h);
            h = fma4(ev.z, ld4(w1c + (4 * kv + 2) * H), h);
            h = fma4(ev.w, ld4(w1c + (4 * kv + 3) * H), h);
        }
        h = relu4(h);

        const float* w2r = W2 + (4 * j4) * R;
        #pragma unroll
        for (int q = 0; q < 4; ++q) {
            const float hq = (q == 0) ? h.x : (q == 1) ? h.y : (q == 2) ? h.z : h.w;
            #pragma unroll
            for (int r4 = 0; r4 < 8; ++r4)
                rf4[r4] = fma4(hq, ld4(w2r + q * R + 4 * r4), rf4[r4]);
        }
    }

    // final relu + transposed LDS stage
    #pragma unroll
    for (int r4 = 0; r4 < 8; ++r4) {
        float4 v = relu4(rf4[r4]);
        lds[(4 * r4 + 0) * 257 + tid] = v.x;
        lds[(4 * r4 + 1) * 257 + tid] = v.y;
        lds[(4 * r4 + 2) * 257 + tid] = v.z;
        lds[(4 * r4 + 3) * 257 + tid] = v.w;
    }
    __syncthreads();

    // segmented reduction: group g handles positions [32g, 32g+32), lane = feature
    const int g = tid >> 5;
    const int f = tid & 31;
    const int base = g * 32;
    float acc = 0.f;
    int cur = rs[base];
    #pragma unroll 1
    for (int i = 0; i < 32; ++i) {
        int rr = rs[base + i];
        float v = lds[f * 257 + base + i];
        if (rr != cur) {
            atomicAdd(rel + ((size_t)b * N + cur) * R + f, acc);
            acc = 0.f;
            cur = rr;
        }
        acc += v;
    }
    atomicAdd(rel + ((size_t)b * N + cur) * R + f, acc);
}

// ---------- node MLP (float4 registers, residual) ----------

__global__ __launch_bounds__(256, 2) void node_kernel(
    const float* __restrict__ particles,
    const float* __restrict__ rel,
    const float* __restrict__ W3, const float* __restrict__ b3,
    const float* __restrict__ W4, const float* __restrict__ b4,
    float* __restrict__ out)
{
    const int idx = blockIdx.x * 256 + threadIdx.x;  // [0, B*N)

    float4 in4[12];   // [particles(4) | rel(8)]
    {
        const float4* pp = reinterpret_cast<const float4*>(particles + (size_t)idx * D);
        #pragma unroll
        for (int q = 0; q < 4; ++q) in4[q] = pp[q];
        const float4* pr = reinterpret_cast<const float4*>(rel + (size_t)idx * R);
        #pragma unroll
        for (int q = 0; q < 8; ++q) in4[4 + q] = pr[q];
    }

    float4 dl4[4];
    #pragma unroll
    for (int q = 0; q < 4; ++q) dl4[q] = ld4(b4 + 4 * q);

    for (int j4 = 0; j4 < H / 4; ++j4) {
        float4 h = ld4(b3 + 4 * j4);
        const float* w3c = W3 + 4 * j4;
        #pragma unroll
        for (int kv = 0; kv < 12; ++kv) {
            const float4 ev = in4[kv];
            h = fma4(ev.x, ld4(w3c + (4 * kv + 0) * H), h);
            h = fma4(ev.y, ld4(w3c + (4 * kv + 1) * H), h);
            h = fma4(ev.z, ld4(w3c + (4 * kv + 2) * H), h);
            h = fma4(ev.w, ld4(w3c + (4 * kv + 3) * H), h);
        }
        h = relu4(h);

        const float* w4r = W4 + (4 * j4) * D;
        #pragma unroll
        for (int q = 0; q < 4; ++q) {
            const float hq = (q == 0) ? h.x : (q == 1) ? h.y : (q == 2) ? h.z : h.w;
            #pragma unroll
            for (int d4 = 0; d4 < 4; ++d4)
                dl4[d4] = fma4(hq, ld4(w4r + q * D + 4 * d4), dl4[d4]);
        }
    }

    float4* po = reinterpret_cast<float4*>(out + (size_t)idx * D);
    #pragma unroll
    for (int q = 0; q < 4; ++q) {
        float4 v = dl4[q];
        float4 pv = in4[q];
        po[q] = float4{pv.x + v.x, pv.y + v.y, pv.z + v.z, pv.w + v.w};
    }
}

// ---------- fallback path (atomics straight to rel; correctness backstop) ----------

__global__ __launch_bounds__(256, 2) void edge_atomic_kernel(
    const float* __restrict__ particles,
    const int*   __restrict__ senders,
    const int*   __restrict__ receivers,
    const float* __restrict__ W1, const float* __restrict__ b1,
    const float* __restrict__ W2, const float* __restrict__ b2,
    float* __restrict__ rel)
{
    const int idx = blockIdx.x * 256 + threadIdx.x;
    const int b = idx >> 18;
    const int e = idx & (E - 1);
    const int s = senders[e];
    const int r = receivers[e];

    float4 ein4[8];
    {
        const float4* ps = reinterpret_cast<const float4*>(particles + ((size_t)b * N + s) * D);
        const float4* pr = reinterpret_cast<const float4*>(particles + ((size_t)b * N + r) * D);
        #pragma unroll
        for (int q = 0; q < 4; ++q) ein4[q] = ps[q];
        #pragma unroll
        for (int q = 0; q < 4; ++q) ein4[4 + q] = pr[q];
    }

    float4 rf4[8];
    #pragma unroll
    for (int q = 0; q < 8; ++q) rf4[q] = ld4(b2 + 4 * q);

    for (int j4 = 0; j4 < H / 4; ++j4) {
        float4 h = ld4(b1 + 4 * j4);
        const float* w1c = W1 + 4 * j4;
        #pragma unroll
        for (int kv = 0; kv < 8; ++kv) {
            const float4 ev = ein4[kv];
            h = fma4(ev.x, ld4(w1c + (4 * kv + 0) * H), h);
            h = fma4(ev.y, ld4(w1c + (4 * kv + 1) * H), h);
            h = fma4(ev.z, ld4(w1c + (4 * kv + 2) * H), h);
            h = fma4(ev.w, ld4(w1c + (4 * kv + 3) * H), h);
        }
        h = relu4(h);
        const float* w2r = W2 + (4 * j4) * R;
        #pragma unroll
        for (int q = 0; q < 4; ++q) {
            const float hq = (q == 0) ? h.x : (q == 1) ? h.y : (q == 2) ? h.z : h.w;
            #pragma unroll
            for (int r4 = 0; r4 < 8; ++r4)
                rf4[r4] = fma4(hq, ld4(w2r + q * R + 4 * r4), rf4[r4]);
        }
    }

    float* dst = rel + ((size_t)b * N + r) * R;
    #pragma unroll
    for (int r4 = 0; r4 < 8; ++r4) {
        float4 v = relu4(rf4[r4]);
        atomicAdd(dst + 4 * r4 + 0, v.x);
        atomicAdd(dst + 4 * r4 + 1, v.y);
        atomicAdd(dst + 4 * r4 + 2, v.z);
        atomicAdd(dst + 4 * r4 + 3, v.w);
    }
}

}  // namespace

extern "C" void kernel_launch(void* const* d_in, const int* in_sizes, int n_in,
                              void* d_out, int out_size, void* d_ws, size_t ws_size,
                              hipStream_t stream) {
    const float* particles = (const float*)d_in[0];
    const int*   senders   = (const int*)d_in[1];
    const int*   receivers = (const int*)d_in[2];
    const float* W1 = (const float*)d_in[3];
    const float* b1 = (const float*)d_in[4];
    const float* W2 = (const float*)d_in[5];
    const float* b2 = (const float*)d_in[6];
    const float* W3 = (const float*)d_in[7];
    const float* b3 = (const float*)d_in[8];
    const float* W4 = (const float*)d_in[9];
    const float* b4 = (const float*)d_in[10];
    float* out = (float*)d_out;

    // workspace layout (256-B aligned slices)
    char* ws = (char*)d_ws;
    size_t off = 0;
    auto take = [&](size_t bytes) -> char* {
        char* p = ws + off;
        off = (off + bytes + 255) & ~(size_t)255;
        return p;
    };
    int*   cnt     = (int*)  take((size_t)N * 4);
    int*   pos     = (int*)  take((size_t)N * 4);
    int*   ssorted = (int*)  take((size_t)E * 4);
    int*   rsorted = (int*)  take((size_t)E * 4);
    float* rel     = (float*)take((size_t)B * N * R * 4);
    const bool fast = (off <= ws_size);

    if (fast) {
        hipMemsetAsync(cnt, 0, (size_t)N * 4, stream);
        hipMemsetAsync(rel, 0, (size_t)B * N * R * 4, stream);
        hist_kernel<<<E / 256, 256, 0, stream>>>(receivers, cnt);
        scan_kernel<<<1, 1024, 0, stream>>>(cnt, pos);
        scatter_kernel<<<E / 256, 256, 0, stream>>>(senders, receivers, pos, ssorted, rsorted);
        edge_fused_kernel<<<(B * E) / 256, 256, 0, stream>>>(
            particles, ssorted, rsorted, W1, b1, W2, b2, rel);
        node_kernel<<<(B * N) / 256, 256, 0, stream>>>(
            particles, rel, W3, b3, W4, b4, out);
    } else {
        float* rel0 = (float*)d_ws;
        hipMemsetAsync(rel0, 0, (size_t)B * N * R * 4, stream);
        edge_atomic_kernel<<<(B * E) / 256, 256, 0, stream>>>(
            particles, senders, receivers, W1, b1, W2, b2, rel0);
        node_kernel<<<(B * N) / 256, 256, 0, stream>>>(
            particles, rel0, W3, b3, W4, b4, out);
    }
}

// Round 4
// 198.730 us; speedup vs baseline: 9.2372x; 1.4997x over previous
//
#include <hip/hip_runtime.h>
#include <hip/hip_bf16.h>

namespace {

constexpr int B = 4;
constexpr int N = 8192;     // 2^13
constexpr int D = 16;
constexpr int R = 32;
constexpr int H = 64;
constexpr int E = 262144;   // 2^18

typedef __attribute__((ext_vector_type(8))) short short8;   // 8 x bf16 (4 VGPRs)
typedef __attribute__((ext_vector_type(4))) float f32x4;    // MFMA accumulator

__device__ __forceinline__ float4 ld4(const float* p) {
    return *reinterpret_cast<const float4*>(p);
}
__device__ __forceinline__ float4 fma4(float a, float4 w, float4 c) {
    return float4{fmaf(a, w.x, c.x), fmaf(a, w.y, c.y),
                  fmaf(a, w.z, c.z), fmaf(a, w.w, c.w)};
}
__device__ __forceinline__ float4 relu4(float4 v) {
    return float4{fmaxf(v.x, 0.f), fmaxf(v.y, 0.f), fmaxf(v.z, 0.f), fmaxf(v.w, 0.f)};
}
__device__ __forceinline__ short bf16s(float f) {
    __hip_bfloat16 h = __float2bfloat16(f);   // RNE
    return __builtin_bit_cast(short, h);
}

// ---------- sort pipeline ----------

__global__ __launch_bounds__(256) void hist_kernel(
    const int* __restrict__ receivers, int* __restrict__ cnt)
{
    int e = blockIdx.x * 256 + threadIdx.x;
    if (e < E) atomicAdd(cnt + receivers[e], 1);
}

// single block, 1024 threads, exclusive scan of 8192 bins -> pos
__global__ __launch_bounds__(1024) void scan_kernel(
    const int* __restrict__ cnt, int* __restrict__ pos)
{
    __shared__ int part[1024];
    const int t = threadIdx.x;
    int local[8];
    int s = 0;
    #pragma unroll
    for (int i = 0; i < 8; ++i) { local[i] = cnt[t * 8 + i]; s += local[i]; }
    part[t] = s;
    __syncthreads();
    for (int off = 1; off < 1024; off <<= 1) {
        int v = (t >= off) ? part[t - off] : 0;
        __syncthreads();
        part[t] += v;
        __syncthreads();
    }
    int base = (t == 0) ? 0 : part[t - 1];
    #pragma unroll
    for (int i = 0; i < 8; ++i) {
        pos[t * 8 + i] = base;
        base += local[i];
    }
}

__global__ __launch_bounds__(256) void scatter_kernel(
    const int* __restrict__ senders, const int* __restrict__ receivers,
    int* __restrict__ pos, int* __restrict__ ssorted, int* __restrict__ rsorted)
{
    int e = blockIdx.x * 256 + threadIdx.x;
    if (e < E) {
        int r = receivers[e];
        int p = atomicAdd(pos + r, 1);
        ssorted[p] = senders[e];
        rsorted[p] = r;
    }
}

// ---------- weight prepack into MFMA fragment layout (bf16) ----------
// w1p: B-operand frags for layer1. ct in [0,4): cols ct*16+(lane&15), k=(lane>>4)*8+j.
// w2p: A-operand frags for layer2 (W2^T). idx=mt*2+kc: m=f=mt*16+(lane&15),
//      k = kc*32+(lane>>4)*8+j  -> value W2[k][f].
__global__ __launch_bounds__(256) void prepack_kernel(
    const float* __restrict__ W1, const float* __restrict__ W2,
    short* __restrict__ w1p, short* __restrict__ w2p)
{
    const int t = threadIdx.x;
    for (int i = t; i < 4 * 64 * 8; i += 256) {
        int j = i & 7, lane = (i >> 3) & 63, ct = i >> 9;
        int k = (lane >> 4) * 8 + j, n = ct * 16 + (lane & 15);
        w1p[i] = bf16s(W1[k * H + n]);
    }
    for (int i = t; i < 4 * 64 * 8; i += 256) {
        int j = i & 7, lane = (i >> 3) & 63, idx = i >> 9;
        int mt = idx >> 1, kc = idx & 1;
        int k = kc * 32 + (lane >> 4) * 8 + j, f = mt * 16 + (lane & 15);
        w2p[i] = bf16s(W2[k * R + f]);
    }
}

// ---------- MFMA edge MLP + segmented reduction ----------
// Block = 256 sorted positions in one batch. Wave w owns positions
// [w*64, w*64+64) as 4 row-tiles of 16 edges.
// Layer1: D1[edge][hidden] = ein @ W1   (4x mfma 16x16x32, K=2D=32)
// h: C-layout -> per-wave LDS transpose -> B-operand layout
// Layer2: D2[f][edge] = W2^T @ h^T      (4x mfma, K=H=64 in 2 chunks)
// D2's C-layout cols are edge positions -> feeds segmented reduce directly.
__global__ __launch_bounds__(256, 2) void edge_mfma_kernel(
    const float* __restrict__ particles,
    const int*   __restrict__ ssorted,
    const int*   __restrict__ rsorted,
    const short* __restrict__ w1p, const float* __restrict__ b1,
    const short* __restrict__ w2p, const float* __restrict__ b2,
    float* __restrict__ rel)
{
    __shared__ float red[R * 257];        // [f][p] reduce stage, 32896 B
    __shared__ short hbuf[4][16 * 72];    // per-wave h transpose, stride 72 (144 B, 16B-aligned rows)
    __shared__ int   rs[256];

    const int tid  = threadIdx.x;
    const int lane = tid & 63;
    const int w    = tid >> 6;
    const int b    = blockIdx.x >> 10;            // 1024 blocks per batch
    const int p0   = (blockIdx.x & 1023) * 256;   // block base sorted position
    rs[tid] = rsorted[p0 + tid];

    const int l15 = lane & 15;
    const int q   = lane >> 4;

    // preload weight fragments (L1-resident, shared by all waves)
    short8 w1f[4], w2f[4];
    #pragma unroll
    for (int ct = 0; ct < 4; ++ct)
        w1f[ct] = *reinterpret_cast<const short8*>(w1p + (ct * 64 + lane) * 8);
    #pragma unroll
    for (int i = 0; i < 4; ++i)
        w2f[i] = *reinterpret_cast<const short8*>(w2p + (i * 64 + lane) * 8);

    // bias in C-layout: layer1 col = hidden = ct*16+l15 (same for all 4 regs);
    // layer2 rows = f = mt*16 + q*4 + reg -> contiguous float4
    float bias1[4];
    #pragma unroll
    for (int ct = 0; ct < 4; ++ct) bias1[ct] = b1[ct * 16 + l15];
    f32x4 bias2[2];
    #pragma unroll
    for (int mt = 0; mt < 2; ++mt) {
        float4 t = ld4(b2 + mt * 16 + q * 4);
        bias2[mt] = f32x4{t.x, t.y, t.z, t.w};
    }

    short* hb = &hbuf[w][0];

    #pragma unroll 1
    for (int t = 0; t < 4; ++t) {
        const int pt = p0 + w * 64 + t * 16;
        // A-frag gather: row m = edge l15, k-chunk q: q0,q1 = sender feats 0:8,8:16;
        // q2,q3 = receiver feats 0:8,8:16
        const int sp = ssorted[pt + l15];
        const int rp = rsorted[pt + l15];
        const int row = (q < 2) ? sp : rp;
        const float* src = particles + ((size_t)b * N + row) * D + (q & 1) * 8;
        float4 a0 = ld4(src), a1 = ld4(src + 4);
        short8 af;
        af[0] = bf16s(a0.x); af[1] = bf16s(a0.y); af[2] = bf16s(a0.z); af[3] = bf16s(a0.w);
        af[4] = bf16s(a1.x); af[5] = bf16s(a1.y); af[6] = bf16s(a1.z); af[7] = bf16s(a1.w);

        // layer1: 4 col-tiles of hidden
        #pragma unroll
        for (int ct = 0; ct < 4; ++ct) {
            f32x4 c = {bias1[ct], bias1[ct], bias1[ct], bias1[ct]};
            c = __builtin_amdgcn_mfma_f32_16x16x32_bf16(af, w1f[ct], c, 0, 0, 0);
            // relu + write to transpose buffer: hb[row=edge][col=hidden] bf16
            #pragma unroll
            for (int rg = 0; rg < 4; ++rg) {
                hb[(q * 4 + rg) * 72 + ct * 16 + l15] = bf16s(fmaxf(c[rg], 0.f));
            }
        }
        // read back as B-operand of layer2: n = edge l15, k = kc*32 + q*8 + j
        short8 h0 = *reinterpret_cast<const short8*>(hb + l15 * 72 + q * 8);
        short8 h1 = *reinterpret_cast<const short8*>(hb + l15 * 72 + 32 + q * 8);

        // layer2: D2[f][edge], K=64 over 2 chunks, 2 f-tiles
        f32x4 r0 = bias2[0], r1 = bias2[1];
        r0 = __builtin_amdgcn_mfma_f32_16x16x32_bf16(w2f[0], h0, r0, 0, 0, 0);
        r0 = __builtin_amdgcn_mfma_f32_16x16x32_bf16(w2f[1], h1, r0, 0, 0, 0);
        r1 = __builtin_amdgcn_mfma_f32_16x16x32_bf16(w2f[2], h0, r1, 0, 0, 0);
        r1 = __builtin_amdgcn_mfma_f32_16x16x32_bf16(w2f[3], h1, r1, 0, 0, 0);

        // relu + stage into reduce LDS: f = mt*16 + q*4 + rg, col = local position
        const int pl = w * 64 + t * 16 + l15;
        #pragma unroll
        for (int rg = 0; rg < 4; ++rg) {
            red[(q * 4 + rg) * 257 + pl]      = fmaxf(r0[rg], 0.f);
            red[(16 + q * 4 + rg) * 257 + pl] = fmaxf(r1[rg], 0.f);
        }
    }
    __syncthreads();

    // segmented reduction: group g = tid>>5 handles positions [32g, 32g+32), lane = feature
    const int g = tid >> 5;
    const int f = tid & 31;
    const int base = g * 32;
    float acc = 0.f;
    int cur = rs[base];
    #pragma unroll 1
    for (int i = 0; i < 32; ++i) {
        int rr = rs[base + i];
        float v = red[f * 257 + base + i];
        if (rr != cur) {
            atomicAdd(rel + ((size_t)b * N + cur) * R + f, acc);
            acc = 0.f;
            cur = rr;
        }
        acc += v;
    }
    atomicAdd(rel + ((size_t)b * N + cur) * R + f, acc);
}

// ---------- node MLP (float4 registers, residual) ----------

__global__ __launch_bounds__(256, 2) void node_kernel(
    const float* __restrict__ particles,
    const float* __restrict__ rel,
    const float* __restrict__ W3, const float* __restrict__ b3,
    const float* __restrict__ W4, const float* __restrict__ b4,
    float* __restrict__ out)
{
    const int idx = blockIdx.x * 256 + threadIdx.x;  // [0, B*N)

    float4 in4[12];   // [particles(4) | rel(8)]
    {
        const float4* pp = reinterpret_cast<const float4*>(particles + (size_t)idx * D);
        #pragma unroll
        for (int q = 0; q < 4; ++q) in4[q] = pp[q];
        const float4* pr = reinterpret_cast<const float4*>(rel + (size_t)idx * R);
        #pragma unroll
        for (int q = 0; q < 8; ++q) in4[4 + q] = pr[q];
    }

    float4 dl4[4];
    #pragma unroll
    for (int q = 0; q < 4; ++q) dl4[q] = ld4(b4 + 4 * q);

    for (int j4 = 0; j4 < H / 4; ++j4) {
        float4 h = ld4(b3 + 4 * j4);
        const float* w3c = W3 + 4 * j4;
        #pragma unroll
        for (int kv = 0; kv < 12; ++kv) {
            const float4 ev = in4[kv];
            h = fma4(ev.x, ld4(w3c + (4 * kv + 0) * H), h);
            h = fma4(ev.y, ld4(w3c + (4 * kv + 1) * H), h);
            h = fma4(ev.z, ld4(w3c + (4 * kv + 2) * H), h);
            h = fma4(ev.w, ld4(w3c + (4 * kv + 3) * H), h);
        }
        h = relu4(h);

        const float* w4r = W4 + (4 * j4) * D;
        #pragma unroll
        for (int q = 0; q < 4; ++q) {
            const float hq = (q == 0) ? h.x : (q == 1) ? h.y : (q == 2) ? h.z : h.w;
            #pragma unroll
            for (int d4 = 0; d4 < 4; ++d4)
                dl4[d4] = fma4(hq, ld4(w4r + q * D + 4 * d4), dl4[d4]);
        }
    }

    float4* po = reinterpret_cast<float4*>(out + (size_t)idx * D);
    #pragma unroll
    for (int q = 0; q < 4; ++q) {
        float4 v = dl4[q];
        float4 pv = in4[q];
        po[q] = float4{pv.x + v.x, pv.y + v.y, pv.z + v.z, pv.w + v.w};
    }
}

// ---------- fallback path (fp32 atomics, correctness backstop) ----------

__global__ __launch_bounds__(256, 2) void edge_atomic_kernel(
    const float* __restrict__ particles,
    const int*   __restrict__ senders,
    const int*   __restrict__ receivers,
    const float* __restrict__ W1, const float* __restrict__ b1,
    const float* __restrict__ W2, const float* __restrict__ b2,
    float* __restrict__ rel)
{
    const int idx = blockIdx.x * 256 + threadIdx.x;
    const int b = idx >> 18;
    const int e = idx & (E - 1);
    const int s = senders[e];
    const int r = receivers[e];

    float4 ein4[8];
    {
        const float4* ps = reinterpret_cast<const float4*>(particles + ((size_t)b * N + s) * D);
        const float4* pr = reinterpret_cast<const float4*>(particles + ((size_t)b * N + r) * D);
        #pragma unroll
        for (int q = 0; q < 4; ++q) ein4[q] = ps[q];
        #pragma unroll
        for (int q = 0; q < 4; ++q) ein4[4 + q] = pr[q];
    }

    float4 rf4[8];
    #pragma unroll
    for (int q = 0; q < 8; ++q) rf4[q] = ld4(b2 + 4 * q);

    for (int j4 = 0; j4 < H / 4; ++j4) {
        float4 h = ld4(b1 + 4 * j4);
        const float* w1c = W1 + 4 * j4;
        #pragma unroll
        for (int kv = 0; kv < 8; ++kv) {
            const float4 ev = ein4[kv];
            h = fma4(ev.x, ld4(w1c + (4 * kv + 0) * H), h);
            h = fma4(ev.y, ld4(w1c + (4 * kv + 1) * H), h);
            h = fma4(ev.z, ld4(w1c + (4 * kv + 2) * H), h);
            h = fma4(ev.w, ld4(w1c + (4 * kv + 3) * H), h);
        }
        h = relu4(h);
        const float* w2r = W2 + (4 * j4) * R;
        #pragma unroll
        for (int q = 0; q < 4; ++q) {
            const float hq = (q == 0) ? h.x : (q == 1) ? h.y : (q == 2) ? h.z : h.w;
            #pragma unroll
            for (int r4 = 0; r4 < 8; ++r4)
                rf4[r4] = fma4(hq, ld4(w2r + q * R + 4 * r4), rf4[r4]);
        }
    }

    float* dst = rel + ((size_t)b * N + r) * R;
    #pragma unroll
    for (int r4 = 0; r4 < 8; ++r4) {
        float4 v = relu4(rf4[r4]);
        atomicAdd(dst + 4 * r4 + 0, v.x);
        atomicAdd(dst + 4 * r4 + 1, v.y);
        atomicAdd(dst + 4 * r4 + 2, v.z);
        atomicAdd(dst + 4 * r4 + 3, v.w);
    }
}

}  // namespace

extern "C" void kernel_launch(void* const* d_in, const int* in_sizes, int n_in,
                              void* d_out, int out_size, void* d_ws, size_t ws_size,
                              hipStream_t stream) {
    const float* particles = (const float*)d_in[0];
    const int*   senders   = (const int*)d_in[1];
    const int*   receivers = (const int*)d_in[2];
    const float* W1 = (const float*)d_in[3];
    const float* b1 = (const float*)d_in[4];
    const float* W2 = (const float*)d_in[5];
    const float* b2 = (const float*)d_in[6];
    const float* W3 = (const float*)d_in[7];
    const float* b3 = (const float*)d_in[8];
    const float* W4 = (const float*)d_in[9];
    const float* b4 = (const float*)d_in[10];
    float* out = (float*)d_out;

    // workspace layout (256-B aligned slices)
    char* ws = (char*)d_ws;
    size_t off = 0;
    auto take = [&](size_t bytes) -> char* {
        char* p = ws + off;
        off = (off + bytes + 255) & ~(size_t)255;
        return p;
    };
    int*   cnt     = (int*)  take((size_t)N * 4);
    int*   pos     = (int*)  take((size_t)N * 4);
    int*   ssorted = (int*)  take((size_t)E * 4);
    int*   rsorted = (int*)  take((size_t)E * 4);
    float* rel     = (float*)take((size_t)B * N * R * 4);
    short* w1p     = (short*)take((size_t)4 * 64 * 8 * 2);
    short* w2p     = (short*)take((size_t)4 * 64 * 8 * 2);
    const bool fast = (off <= ws_size);

    if (fast) {
        hipMemsetAsync(cnt, 0, (size_t)N * 4, stream);
        hipMemsetAsync(rel, 0, (size_t)B * N * R * 4, stream);
        hist_kernel<<<E / 256, 256, 0, stream>>>(receivers, cnt);
        prepack_kernel<<<1, 256, 0, stream>>>(W1, W2, w1p, w2p);
        scan_kernel<<<1, 1024, 0, stream>>>(cnt, pos);
        scatter_kernel<<<E / 256, 256, 0, stream>>>(senders, receivers, pos, ssorted, rsorted);
        edge_mfma_kernel<<<(B * E) / 256, 256, 0, stream>>>(
            particles, ssorted, rsorted, w1p, b1, w2p, b2, rel);
        node_kernel<<<(B * N) / 256, 256, 0, stream>>>(
            particles, rel, W3, b3, W4, b4, out);
    } else {
        float* rel0 = (float*)d_ws;
        hipMemsetAsync(rel0, 0, (size_t)B * N * R * 4, stream);
        edge_atomic_kernel<<<(B * E) / 256, 256, 0, stream>>>(
            particles, senders, receivers, W1, b1, W2, b2, rel0);
        node_kernel<<<(B * N) / 256, 256, 0, stream>>>(
            particles, rel0, W3, b3, W4, b4, out);
    }
}

// Round 5
// 150.676 us; speedup vs baseline: 12.1832x; 1.3189x over previous
//
#include <hip/hip_runtime.h>
#include <hip/hip_bf16.h>

namespace {

constexpr int B = 4;
constexpr int N = 8192;     // 2^13
constexpr int D = 16;
constexpr int R = 32;
constexpr int H = 64;
constexpr int E = 262144;   // 2^18

typedef __attribute__((ext_vector_type(8))) short short8;   // 8 x bf16 (4 VGPRs)
typedef __attribute__((ext_vector_type(4))) float f32x4;    // MFMA accumulator

__device__ __forceinline__ float4 ld4(const float* p) {
    return *reinterpret_cast<const float4*>(p);
}
__device__ __forceinline__ float4 fma4(float a, float4 w, float4 c) {
    return float4{fmaf(a, w.x, c.x), fmaf(a, w.y, c.y),
                  fmaf(a, w.z, c.z), fmaf(a, w.w, c.w)};
}
__device__ __forceinline__ float4 relu4(float4 v) {
    return float4{fmaxf(v.x, 0.f), fmaxf(v.y, 0.f), fmaxf(v.z, 0.f), fmaxf(v.w, 0.f)};
}
__device__ __forceinline__ short bf16s(float f) {
    __hip_bfloat16 h = __float2bfloat16(f);   // RNE
    return __builtin_bit_cast(short, h);
}
__device__ __forceinline__ short8 pack8(float4 a, float4 b) {
    short8 o;
    o[0] = bf16s(a.x); o[1] = bf16s(a.y); o[2] = bf16s(a.z); o[3] = bf16s(a.w);
    o[4] = bf16s(b.x); o[5] = bf16s(b.y); o[6] = bf16s(b.z); o[7] = bf16s(b.w);
    return o;
}

// ---------- hist + weight prepack (fused; block 1024 does prepack) ----------
// Fragment layouts (mfma_f32_16x16x32_bf16, verified m89):
//   A-frag: m = lane&15, k = (lane>>4)*8 + j
//   B-frag: n = lane&15, k = (lane>>4)*8 + j
//   C/D:    col = lane&15, row = (lane>>4)*4 + reg
__global__ __launch_bounds__(256) void hist_prepack_kernel(
    const int* __restrict__ receivers, int* __restrict__ cnt,
    const float* __restrict__ W1, const float* __restrict__ W2,
    const float* __restrict__ W3, const float* __restrict__ W4,
    short* __restrict__ w1p, short* __restrict__ w2p,
    short* __restrict__ w3p, short* __restrict__ w4p)
{
    if (blockIdx.x < 1024) {
        int e = blockIdx.x * 256 + threadIdx.x;
        atomicAdd(cnt + receivers[e], 1);
        return;
    }
    const int t = threadIdx.x;
    // w1p: B-frags of W1 (32x64), 4 col-tiles
    for (int i = t; i < 4 * 64 * 8; i += 256) {
        int j = i & 7, lane = (i >> 3) & 63, ct = i >> 9;
        int k = (lane >> 4) * 8 + j, n = ct * 16 + (lane & 15);
        w1p[i] = bf16s(W1[k * H + n]);
    }
    // w2p: A-frags of W2^T (W2 is 64x32), idx = mt*2+kc
    for (int i = t; i < 4 * 64 * 8; i += 256) {
        int j = i & 7, lane = (i >> 3) & 63, idx = i >> 9;
        int mt = idx >> 1, kc = idx & 1;
        int k = kc * 32 + (lane >> 4) * 8 + j, f = mt * 16 + (lane & 15);
        w2p[i] = bf16s(W2[k * R + f]);
    }
    // w3p: B-frags of W3 (48x64), idx = ct*2+kc, zero-pad k>=48
    for (int i = t; i < 8 * 64 * 8; i += 256) {
        int j = i & 7, lane = (i >> 3) & 63, idx = i >> 9;
        int ct = idx >> 1, kc = idx & 1;
        int k = kc * 32 + (lane >> 4) * 8 + j, n = ct * 16 + (lane & 15);
        w3p[i] = (k < D + R) ? bf16s(W3[k * H + n]) : (short)0;
    }
    // w4p: A-frags of W4^T (W4 is 64x16), idx = kc
    for (int i = t; i < 2 * 64 * 8; i += 256) {
        int j = i & 7, lane = (i >> 3) & 63, kc = i >> 9;
        int k = kc * 32 + (lane >> 4) * 8 + j, d = lane & 15;
        w4p[i] = bf16s(W4[k * D + d]);
    }
}

// single block, 1024 threads, wave-shuffle exclusive scan of 8192 bins -> pos
__global__ __launch_bounds__(1024) void scan_kernel(
    const int* __restrict__ cnt, int* __restrict__ pos)
{
    __shared__ int wtot[16];
    const int t = threadIdx.x;
    const int lane = t & 63;
    int local[8];
    int s = 0;
    #pragma unroll
    for (int i = 0; i < 8; ++i) { local[i] = cnt[t * 8 + i]; s += local[i]; }
    int incl = s;
    #pragma unroll
    for (int d = 1; d < 64; d <<= 1) {
        int v = __shfl_up(incl, d, 64);
        if (lane >= d) incl += v;
    }
    if (lane == 63) wtot[t >> 6] = incl;
    __syncthreads();
    int base = incl - s;
    const int wv = t >> 6;
    #pragma unroll
    for (int i = 0; i < 16; ++i) base += (i < wv) ? wtot[i] : 0;
    #pragma unroll
    for (int i = 0; i < 8; ++i) {
        pos[t * 8 + i] = base;
        base += local[i];
    }
}

__global__ __launch_bounds__(256) void scatter_kernel(
    const int* __restrict__ senders, const int* __restrict__ receivers,
    int* __restrict__ pos, int* __restrict__ ssorted, int* __restrict__ rsorted)
{
    int e = blockIdx.x * 256 + threadIdx.x;
    if (e < E) {
        int r = receivers[e];
        int p = atomicAdd(pos + r, 1);
        ssorted[p] = senders[e];
        rsorted[p] = r;
    }
}

// ---------- MFMA edge MLP + segmented reduction ----------
// Block = 256 sorted positions in one batch; wave w owns 4 row-tiles of 16.
// All gathers hoisted ahead of the MFMA chain (one global-latency exposure).
__global__ __launch_bounds__(256, 3) void edge_mfma_kernel(
    const float* __restrict__ particles,
    const int*   __restrict__ ssorted,
    const int*   __restrict__ rsorted,
    const short* __restrict__ w1p, const float* __restrict__ b1,
    const short* __restrict__ w2p, const float* __restrict__ b2,
    float* __restrict__ rel)
{
    __shared__ float red[R * 257];        // [f][p] reduce stage
    __shared__ short hbuf[4][16 * 72];    // per-wave h transpose
    __shared__ int   rs[256];

    const int tid  = threadIdx.x;
    const int lane = tid & 63;
    const int w    = tid >> 6;
    const int b    = blockIdx.x >> 10;            // 1024 blocks per batch
    const int p0   = (blockIdx.x & 1023) * 256;
    const int l15  = lane & 15;
    const int q    = lane >> 4;

    const int sval = ssorted[p0 + tid];
    const int rval = rsorted[p0 + tid];
    rs[tid] = rval;

    // hoisted gather: distribute rows via shfl, issue all 8 dwordx4 loads
    float4 a0[4], a1[4];
    #pragma unroll
    for (int t = 0; t < 4; ++t) {
        int srow = __shfl(sval, t * 16 + l15);
        int rrow = __shfl(rval, t * 16 + l15);
        int row = (q < 2) ? srow : rrow;
        const float* src = particles + ((size_t)b * N + row) * D + (q & 1) * 8;
        a0[t] = ld4(src);
        a1[t] = ld4(src + 4);
    }

    // weight fragments (L2-hot, coalesced)
    short8 w1f[4], w2f[4];
    #pragma unroll
    for (int ct = 0; ct < 4; ++ct)
        w1f[ct] = *reinterpret_cast<const short8*>(w1p + (ct * 64 + lane) * 8);
    #pragma unroll
    for (int i = 0; i < 4; ++i)
        w2f[i] = *reinterpret_cast<const short8*>(w2p + (i * 64 + lane) * 8);

    float bias1[4];
    #pragma unroll
    for (int ct = 0; ct < 4; ++ct) bias1[ct] = b1[ct * 16 + l15];
    f32x4 bias2[2];
    #pragma unroll
    for (int mt = 0; mt < 2; ++mt) {
        float4 t4 = ld4(b2 + mt * 16 + q * 4);
        bias2[mt] = f32x4{t4.x, t4.y, t4.z, t4.w};
    }

    short8 af[4];
    #pragma unroll
    for (int t = 0; t < 4; ++t) af[t] = pack8(a0[t], a1[t]);

    short* hb = &hbuf[w][0];

    #pragma unroll
    for (int t = 0; t < 4; ++t) {
        // layer1: D1[edge][hidden], 4 col-tiles, K=32
        #pragma unroll
        for (int ct = 0; ct < 4; ++ct) {
            f32x4 c = {bias1[ct], bias1[ct], bias1[ct], bias1[ct]};
            c = __builtin_amdgcn_mfma_f32_16x16x32_bf16(af[t], w1f[ct], c, 0, 0, 0);
            #pragma unroll
            for (int rg = 0; rg < 4; ++rg)
                hb[(q * 4 + rg) * 72 + ct * 16 + l15] = bf16s(fmaxf(c[rg], 0.f));
        }
        short8 h0 = *reinterpret_cast<const short8*>(hb + l15 * 72 + q * 8);
        short8 h1 = *reinterpret_cast<const short8*>(hb + l15 * 72 + 32 + q * 8);

        // layer2: D2[f][edge] = W2^T @ h^T, K=64
        f32x4 r0 = bias2[0], r1 = bias2[1];
        r0 = __builtin_amdgcn_mfma_f32_16x16x32_bf16(w2f[0], h0, r0, 0, 0, 0);
        r0 = __builtin_amdgcn_mfma_f32_16x16x32_bf16(w2f[1], h1, r0, 0, 0, 0);
        r1 = __builtin_amdgcn_mfma_f32_16x16x32_bf16(w2f[2], h0, r1, 0, 0, 0);
        r1 = __builtin_amdgcn_mfma_f32_16x16x32_bf16(w2f[3], h1, r1, 0, 0, 0);

        const int pl = w * 64 + t * 16 + l15;
        #pragma unroll
        for (int rg = 0; rg < 4; ++rg) {
            red[(q * 4 + rg) * 257 + pl]      = fmaxf(r0[rg], 0.f);
            red[(16 + q * 4 + rg) * 257 + pl] = fmaxf(r1[rg], 0.f);
        }
    }
    __syncthreads();

    // segmented reduction: group g handles positions [32g, 32g+32), lane = feature
    const int g = tid >> 5;
    const int f = tid & 31;
    const int base = g * 32;
    float acc = 0.f;
    int cur = rs[base];
    #pragma unroll 1
    for (int i = 0; i < 32; ++i) {
        int rr = rs[base + i];
        float v = red[f * 257 + base + i];
        if (rr != cur) {
            atomicAdd(rel + ((size_t)b * N + cur) * R + f, acc);
            acc = 0.f;
            cur = rr;
        }
        acc += v;
    }
    atomicAdd(rel + ((size_t)b * N + cur) * R + f, acc);
}

// ---------- MFMA node MLP: one 16-node tile per wave ----------
// dyn_in = [particles(16) | rel(32)], K=48 zero-padded to 64.
// layer1: D[node][hidden] (8 MFMAs), transpose, layer2: delta^T[d][node] (2 MFMAs).
__global__ __launch_bounds__(256, 4) void node_mfma_kernel(
    const float* __restrict__ particles,
    const float* __restrict__ rel,
    const short* __restrict__ w3p, const float* __restrict__ b3,
    const short* __restrict__ w4p, const float* __restrict__ b4,
    float* __restrict__ out)
{
    __shared__ short hbuf[4][16 * 72];

    const int tid  = threadIdx.x;
    const int lane = tid & 63;
    const int w    = tid >> 6;
    const int tile = blockIdx.x * 4 + w;        // [0, B*N/16)
    const int b    = tile >> 9;                 // 512 tiles per batch
    const int l15  = lane & 15;
    const int q    = lane >> 4;
    const int node = (tile & 511) * 16 + l15;

    const float* prow = particles + ((size_t)b * N + node) * D;
    const float* rrow = rel + ((size_t)b * N + node) * R;

    // A-frag chunk0: k=0..31 -> q0: p[0:8], q1: p[8:16], q2: rel[0:8], q3: rel[8:16]
    const float* src0 = (q < 2) ? (prow + (q & 1) * 8) : (rrow + (q & 1) * 8);
    float4 c0a = ld4(src0), c0b = ld4(src0 + 4);
    // chunk1: k=32..47 -> rel[16:32] (q<2), k>=48 zero
    float4 c1a = {0.f, 0.f, 0.f, 0.f}, c1b = {0.f, 0.f, 0.f, 0.f};
    if (q < 2) { c1a = ld4(rrow + 16 + q * 8); c1b = ld4(rrow + 20 + q * 8); }

    short8 w3f[8], w4f[2];
    #pragma unroll
    for (int i = 0; i < 8; ++i)
        w3f[i] = *reinterpret_cast<const short8*>(w3p + (i * 64 + lane) * 8);
    #pragma unroll
    for (int i = 0; i < 2; ++i)
        w4f[i] = *reinterpret_cast<const short8*>(w4p + (i * 64 + lane) * 8);

    float bias3[4];
    #pragma unroll
    for (int ct = 0; ct < 4; ++ct) bias3[ct] = b3[ct * 16 + l15];
    f32x4 bias4;
    { float4 t4 = ld4(b4 + q * 4); bias4 = f32x4{t4.x, t4.y, t4.z, t4.w}; }

    short8 a0 = pack8(c0a, c0b);
    short8 a1 = pack8(c1a, c1b);

    short* hb = &hbuf[w][0];
    #pragma unroll
    for (int ct = 0; ct < 4; ++ct) {
        f32x4 c = {bias3[ct], bias3[ct], bias3[ct], bias3[ct]};
        c = __builtin_amdgcn_mfma_f32_16x16x32_bf16(a0, w3f[ct * 2 + 0], c, 0, 0, 0);
        c = __builtin_amdgcn_mfma_f32_16x16x32_bf16(a1, w3f[ct * 2 + 1], c, 0, 0, 0);
        #pragma unroll
        for (int rg = 0; rg < 4; ++rg)
            hb[(q * 4 + rg) * 72 + ct * 16 + l15] = bf16s(fmaxf(c[rg], 0.f));
    }
    short8 h0 = *reinterpret_cast<const short8*>(hb + l15 * 72 + q * 8);
    short8 h1 = *reinterpret_cast<const short8*>(hb + l15 * 72 + 32 + q * 8);

    f32x4 r = bias4;
    r = __builtin_amdgcn_mfma_f32_16x16x32_bf16(w4f[0], h0, r, 0, 0, 0);
    r = __builtin_amdgcn_mfma_f32_16x16x32_bf16(w4f[1], h1, r, 0, 0, 0);

    // residual + store: col = node, rows d = q*4..q*4+3 -> one float4
    const float* pi = prow + q * 4;
    float4 pv = ld4(pi);
    float4* po = reinterpret_cast<float4*>(out + ((size_t)b * N + node) * D + q * 4);
    *po = float4{pv.x + r[0], pv.y + r[1], pv.z + r[2], pv.w + r[3]};
}

// ---------- fallback path (fp32, correctness backstop) ----------

__global__ __launch_bounds__(256, 2) void edge_atomic_kernel(
    const float* __restrict__ particles,
    const int*   __restrict__ senders,
    const int*   __restrict__ receivers,
    const float* __restrict__ W1, const float* __restrict__ b1,
    const float* __restrict__ W2, const float* __restrict__ b2,
    float* __restrict__ rel)
{
    const int idx = blockIdx.x * 256 + threadIdx.x;
    const int b = idx >> 18;
    const int e = idx & (E - 1);
    const int s = senders[e];
    const int r = receivers[e];

    float4 ein4[8];
    {
        const float4* ps = reinterpret_cast<const float4*>(particles + ((size_t)b * N + s) * D);
        const float4* pr = reinterpret_cast<const float4*>(particles + ((size_t)b * N + r) * D);
        #pragma unroll
        for (int qq = 0; qq < 4; ++qq) ein4[qq] = ps[qq];
        #pragma unroll
        for (int qq = 0; qq < 4; ++qq) ein4[4 + qq] = pr[qq];
    }
    float4 rf4[8];
    #pragma unroll
    for (int qq = 0; qq < 8; ++qq) rf4[qq] = ld4(b2 + 4 * qq);

    for (int j4 = 0; j4 < H / 4; ++j4) {
        float4 h = ld4(b1 + 4 * j4);
        const float* w1c = W1 + 4 * j4;
        #pragma unroll
        for (int kv = 0; kv < 8; ++kv) {
            const float4 ev = ein4[kv];
            h = fma4(ev.x, ld4(w1c + (4 * kv + 0) * H), h);
            h = fma4(ev.y, ld4(w1c + (4 * kv + 1) * H), h);
            h = fma4(ev.z, ld4(w1c + (4 * kv + 2) * H), h);
            h = fma4(ev.w, ld4(w1c + (4 * kv + 3) * H), h);
        }
        h = relu4(h);
        const float* w2r = W2 + (4 * j4) * R;
        #pragma unroll
        for (int qq = 0; qq < 4; ++qq) {
            const float hq = (qq == 0) ? h.x : (qq == 1) ? h.y : (qq == 2) ? h.z : h.w;
            #pragma unroll
            for (int r4 = 0; r4 < 8; ++r4)
                rf4[r4] = fma4(hq, ld4(w2r + qq * R + 4 * r4), rf4[r4]);
        }
    }
    float* dst = rel + ((size_t)b * N + r) * R;
    #pragma unroll
    for (int r4 = 0; r4 < 8; ++r4) {
        float4 v = relu4(rf4[r4]);
        atomicAdd(dst + 4 * r4 + 0, v.x);
        atomicAdd(dst + 4 * r4 + 1, v.y);
        atomicAdd(dst + 4 * r4 + 2, v.z);
        atomicAdd(dst + 4 * r4 + 3, v.w);
    }
}

__global__ __launch_bounds__(256, 2) void node_valu_kernel(
    const float* __restrict__ particles,
    const float* __restrict__ rel,
    const float* __restrict__ W3, const float* __restrict__ b3,
    const float* __restrict__ W4, const float* __restrict__ b4,
    float* __restrict__ out)
{
    const int idx = blockIdx.x * 256 + threadIdx.x;
    float4 in4[12];
    {
        const float4* pp = reinterpret_cast<const float4*>(particles + (size_t)idx * D);
        #pragma unroll
        for (int qq = 0; qq < 4; ++qq) in4[qq] = pp[qq];
        const float4* pr = reinterpret_cast<const float4*>(rel + (size_t)idx * R);
        #pragma unroll
        for (int qq = 0; qq < 8; ++qq) in4[4 + qq] = pr[qq];
    }
    float4 dl4[4];
    #pragma unroll
    for (int qq = 0; qq < 4; ++qq) dl4[qq] = ld4(b4 + 4 * qq);

    for (int j4 = 0; j4 < H / 4; ++j4) {
        float4 h = ld4(b3 + 4 * j4);
        const float* w3c = W3 + 4 * j4;
        #pragma unroll
        for (int kv = 0; kv < 12; ++kv) {
            const float4 ev = in4[kv];
            h = fma4(ev.x, ld4(w3c + (4 * kv + 0) * H), h);
            h = fma4(ev.y, ld4(w3c + (4 * kv + 1) * H), h);
            h = fma4(ev.z, ld4(w3c + (4 * kv + 2) * H), h);
            h = fma4(ev.w, ld4(w3c + (4 * kv + 3) * H), h);
        }
        h = relu4(h);
        const float* w4r = W4 + (4 * j4) * D;
        #pragma unroll
        for (int qq = 0; qq < 4; ++qq) {
            const float hq = (qq == 0) ? h.x : (qq == 1) ? h.y : (qq == 2) ? h.z : h.w;
            #pragma unroll
            for (int d4 = 0; d4 < 4; ++d4)
                dl4[d4] = fma4(hq, ld4(w4r + qq * D + 4 * d4), dl4[d4]);
        }
    }
    float4* po = reinterpret_cast<float4*>(out + (size_t)idx * D);
    #pragma unroll
    for (int qq = 0; qq < 4; ++qq) {
        float4 v = dl4[qq];
        float4 pv = in4[qq];
        po[qq] = float4{pv.x + v.x, pv.y + v.y, pv.z + v.z, pv.w + v.w};
    }
}

}  // namespace

extern "C" void kernel_launch(void* const* d_in, const int* in_sizes, int n_in,
                              void* d_out, int out_size, void* d_ws, size_t ws_size,
                              hipStream_t stream) {
    const float* particles = (const float*)d_in[0];
    const int*   senders   = (const int*)d_in[1];
    const int*   receivers = (const int*)d_in[2];
    const float* W1 = (const float*)d_in[3];
    const float* b1 = (const float*)d_in[4];
    const float* W2 = (const float*)d_in[5];
    const float* b2 = (const float*)d_in[6];
    const float* W3 = (const float*)d_in[7];
    const float* b3 = (const float*)d_in[8];
    const float* W4 = (const float*)d_in[9];
    const float* b4 = (const float*)d_in[10];
    float* out = (float*)d_out;

    // workspace layout (256-B aligned slices)
    char* ws = (char*)d_ws;
    size_t off = 0;
    auto take = [&](size_t bytes) -> char* {
        char* p = ws + off;
        off = (off + bytes + 255) & ~(size_t)255;
        return p;
    };
    int*   cnt     = (int*)  take((size_t)N * 4);
    int*   pos     = (int*)  take((size_t)N * 4);
    int*   ssorted = (int*)  take((size_t)E * 4);
    int*   rsorted = (int*)  take((size_t)E * 4);
    float* rel     = (float*)take((size_t)B * N * R * 4);
    short* w1p     = (short*)take((size_t)4 * 64 * 8 * 2);
    short* w2p     = (short*)take((size_t)4 * 64 * 8 * 2);
    short* w3p     = (short*)take((size_t)8 * 64 * 8 * 2);
    short* w4p     = (short*)take((size_t)2 * 64 * 8 * 2);
    const bool fast = (off <= ws_size);

    if (fast) {
        hipMemsetAsync(cnt, 0, (size_t)N * 4, stream);
        hipMemsetAsync(rel, 0, (size_t)B * N * R * 4, stream);
        hist_prepack_kernel<<<1025, 256, 0, stream>>>(
            receivers, cnt, W1, W2, W3, W4, w1p, w2p, w3p, w4p);
        scan_kernel<<<1, 1024, 0, stream>>>(cnt, pos);
        scatter_kernel<<<E / 256, 256, 0, stream>>>(senders, receivers, pos, ssorted, rsorted);
        edge_mfma_kernel<<<(B * E) / 256, 256, 0, stream>>>(
            particles, ssorted, rsorted, w1p, b1, w2p, b2, rel);
        node_mfma_kernel<<<(B * N / 16) / 4, 256, 0, stream>>>(
            particles, rel, w3p, b3, w4p, b4, out);
    } else {
        float* rel0 = (float*)d_ws;
        hipMemsetAsync(rel0, 0, (size_t)B * N * R * 4, stream);
        edge_atomic_kernel<<<(B * E) / 256, 256, 0, stream>>>(
            particles, senders, receivers, W1, b1, W2, b2, rel0);
        node_valu_kernel<<<(B * N) / 256, 256, 0, stream>>>(
            particles, rel0, W3, b3, W4, b4, out);
    }
}

// Round 6
// 139.975 us; speedup vs baseline: 13.1146x; 1.0764x over previous
//
#include <hip/hip_runtime.h>
#include <hip/hip_bf16.h>

namespace {

constexpr int B = 4;
constexpr int N = 8192;     // 2^13
constexpr int D = 16;
constexpr int R = 32;
constexpr int H = 64;
constexpr int E = 262144;   // 2^18

typedef __attribute__((ext_vector_type(8))) short short8;   // 8 x bf16 (4 VGPRs)
typedef __attribute__((ext_vector_type(4))) short short4v;  // 4 x bf16 (2 VGPRs)
typedef __attribute__((ext_vector_type(4))) float f32x4;    // MFMA accumulator

__device__ __forceinline__ float4 ld4(const float* p) {
    return *reinterpret_cast<const float4*>(p);
}
__device__ __forceinline__ float4 fma4(float a, float4 w, float4 c) {
    return float4{fmaf(a, w.x, c.x), fmaf(a, w.y, c.y),
                  fmaf(a, w.z, c.z), fmaf(a, w.w, c.w)};
}
__device__ __forceinline__ float4 relu4(float4 v) {
    return float4{fmaxf(v.x, 0.f), fmaxf(v.y, 0.f), fmaxf(v.z, 0.f), fmaxf(v.w, 0.f)};
}
__device__ __forceinline__ short bf16s(float f) {
    __hip_bfloat16 h = __float2bfloat16(f);   // RNE
    return __builtin_bit_cast(short, h);
}
__device__ __forceinline__ short8 pack8(float4 a, float4 b) {
    short8 o;
    o[0] = bf16s(a.x); o[1] = bf16s(a.y); o[2] = bf16s(a.z); o[3] = bf16s(a.w);
    o[4] = bf16s(b.x); o[5] = bf16s(b.y); o[6] = bf16s(b.z); o[7] = bf16s(b.w);
    return o;
}
// relu + pack 4 accumulator floats into 4 bf16 (for one ds_write_b64)
__device__ __forceinline__ short4v pack4_relu(f32x4 c) {
    short4v o;
    o[0] = bf16s(fmaxf(c[0], 0.f)); o[1] = bf16s(fmaxf(c[1], 0.f));
    o[2] = bf16s(fmaxf(c[2], 0.f)); o[3] = bf16s(fmaxf(c[3], 0.f));
    return o;
}

constexpr int RED_S = 260;   // red stride (floats); %4==0 so b128 stays 16B-aligned

// ---------- hist + weight prepack + rel zero (fused) ----------
// Fragment mapping (mfma_f32_16x16x32_bf16, verified m89):
//   A/B-frag: m|n = lane&15, k = (lane>>4)*8 + j
//   C/D:      col = lane&15, row = (lane>>4)*4 + reg
// NOTE: A-frag of Wᵀ m-tile == B-frag of W col-tile (identical mapping),
// so these packs serve both orientations.
__global__ __launch_bounds__(256) void hist_prepack_kernel(
    const int* __restrict__ receivers, int* __restrict__ cnt,
    const float* __restrict__ W1, const float* __restrict__ W2,
    const float* __restrict__ W3, const float* __restrict__ W4,
    short* __restrict__ w1p, short* __restrict__ w2p,
    short* __restrict__ w3p, short* __restrict__ w4p,
    float4* __restrict__ relz)
{
    if (blockIdx.x < 1024) {
        int e = blockIdx.x * 256 + threadIdx.x;
        atomicAdd(cnt + receivers[e], 1);
        return;
    }
    if (blockIdx.x >= 1025) {
        // zero rel: B*N*R floats = 262144 float4, 128 blocks x 256 t x 8 iters
        const int base = (blockIdx.x - 1025) * 256 + threadIdx.x;
        #pragma unroll
        for (int i = 0; i < 8; ++i)
            relz[base + i * 32768] = float4{0.f, 0.f, 0.f, 0.f};
        return;
    }
    const int t = threadIdx.x;
    // w1p[ct]: W1 (32x64) frags: value W1[k][ct*16 + l15]
    for (int i = t; i < 4 * 64 * 8; i += 256) {
        int j = i & 7, lane = (i >> 3) & 63, ct = i >> 9;
        int k = (lane >> 4) * 8 + j, n = ct * 16 + (lane & 15);
        w1p[i] = bf16s(W1[k * H + n]);
    }
    // w2p[ct*2+kc]: W2 (64x32) frags: value W2[kc*32+k][ct*16 + l15]
    for (int i = t; i < 4 * 64 * 8; i += 256) {
        int j = i & 7, lane = (i >> 3) & 63, idx = i >> 9;
        int ct = idx >> 1, kc = idx & 1;
        int k = kc * 32 + (lane >> 4) * 8 + j, f = ct * 16 + (lane & 15);
        w2p[i] = bf16s(W2[k * R + f]);
    }
    // w3p[ct*2+kc]: W3 (48x64) frags, zero-pad k>=48
    for (int i = t; i < 8 * 64 * 8; i += 256) {
        int j = i & 7, lane = (i >> 3) & 63, idx = i >> 9;
        int ct = idx >> 1, kc = idx & 1;
        int k = kc * 32 + (lane >> 4) * 8 + j, n = ct * 16 + (lane & 15);
        w3p[i] = (k < D + R) ? bf16s(W3[k * H + n]) : (short)0;
    }
    // w4p[kc]: W4 (64x16) frags: value W4[kc*32+k][l15]
    for (int i = t; i < 2 * 64 * 8; i += 256) {
        int j = i & 7, lane = (i >> 3) & 63, kc = i >> 9;
        int k = kc * 32 + (lane >> 4) * 8 + j, d = lane & 15;
        w4p[i] = bf16s(W4[k * D + d]);
    }
}

// single block, 1024 threads, wave-shuffle exclusive scan of 8192 bins -> pos
__global__ __launch_bounds__(1024) void scan_kernel(
    const int* __restrict__ cnt, int* __restrict__ pos)
{
    __shared__ int wtot[16];
    const int t = threadIdx.x;
    const int lane = t & 63;
    int local[8];
    int s = 0;
    #pragma unroll
    for (int i = 0; i < 8; ++i) { local[i] = cnt[t * 8 + i]; s += local[i]; }
    int incl = s;
    #pragma unroll
    for (int d = 1; d < 64; d <<= 1) {
        int v = __shfl_up(incl, d, 64);
        if (lane >= d) incl += v;
    }
    if (lane == 63) wtot[t >> 6] = incl;
    __syncthreads();
    int base = incl - s;
    const int wv = t >> 6;
    #pragma unroll
    for (int i = 0; i < 16; ++i) base += (i < wv) ? wtot[i] : 0;
    #pragma unroll
    for (int i = 0; i < 8; ++i) {
        pos[t * 8 + i] = base;
        base += local[i];
    }
}

__global__ __launch_bounds__(256) void scatter_kernel(
    const int* __restrict__ senders, const int* __restrict__ receivers,
    int* __restrict__ pos, int2* __restrict__ sr)
{
    int e = blockIdx.x * 256 + threadIdx.x;
    if (e < E) {
        int r = receivers[e];
        int p = atomicAdd(pos + r, 1);
        sr[p] = int2{senders[e], r};
    }
}

// ---------- MFMA edge MLP + segmented reduction ----------
// Block = 256 sorted positions in one batch; wave w owns 4 row-tiles of 16.
// Layer1: D1[hidden][edge] = W1^T(A) @ ein^T(B) -> hbuf via ds_write_b64
// Layer2: D2[edge][f]      = h(A) @ W2(B)       -> red  via ds_write_b128
__global__ __launch_bounds__(256, 3) void edge_mfma_kernel(
    const float* __restrict__ particles,
    const int2*  __restrict__ sr,
    const short* __restrict__ w1p, const float* __restrict__ b1,
    const short* __restrict__ w2p, const float* __restrict__ b2,
    float* __restrict__ rel)
{
    __shared__ float red[31 * RED_S + 256];   // [f][pos], stride 260
    __shared__ short hbuf[4][16 * 72];        // per-wave [edge][hidden], stride 72
    __shared__ int   rs[256];

    const int tid  = threadIdx.x;
    const int lane = tid & 63;
    const int w    = tid >> 6;
    const int b    = blockIdx.x >> 10;            // 1024 blocks per batch
    const int p0   = (blockIdx.x & 1023) * 256;
    const int l15  = lane & 15;
    const int q    = lane >> 4;

    const int2 srv = sr[p0 + tid];
    const int sval = srv.x;
    const int rval = srv.y;
    rs[tid] = rval;

    // hoisted gather: distribute rows via shfl, issue all 8 dwordx4 loads
    float4 a0[4], a1[4];
    #pragma unroll
    for (int t = 0; t < 4; ++t) {
        int srow = __shfl(sval, t * 16 + l15);
        int rrow = __shfl(rval, t * 16 + l15);
        int row = (q < 2) ? srow : rrow;
        const float* src = particles + ((size_t)b * N + row) * D + (q & 1) * 8;
        a0[t] = ld4(src);
        a1[t] = ld4(src + 4);
    }

    // weight fragments (L2-hot, coalesced)
    short8 w1f[4], w2f[4];
    #pragma unroll
    for (int mt = 0; mt < 4; ++mt)
        w1f[mt] = *reinterpret_cast<const short8*>(w1p + (mt * 64 + lane) * 8);
    #pragma unroll
    for (int i = 0; i < 4; ++i)
        w2f[i] = *reinterpret_cast<const short8*>(w2p + (i * 64 + lane) * 8);

    // bias1: D1 rows = hidden = mt*16 + q*4 + rg
    f32x4 bias1[4];
    #pragma unroll
    for (int mt = 0; mt < 4; ++mt) {
        float4 t4 = ld4(b1 + mt * 16 + q * 4);
        bias1[mt] = f32x4{t4.x, t4.y, t4.z, t4.w};
    }
    // bias2: D2 cols = f = ct*16 + l15 (broadcast across the 4 row-regs)
    const float bias2a = b2[l15];
    const float bias2b = b2[16 + l15];

    short8 af[4];
    #pragma unroll
    for (int t = 0; t < 4; ++t) af[t] = pack8(a0[t], a1[t]);

    short* hb = &hbuf[w][0];

    #pragma unroll
    for (int t = 0; t < 4; ++t) {
        // layer1: 4 hidden m-tiles, K=32; C cols = edge, rows = hidden
        #pragma unroll
        for (int mt = 0; mt < 4; ++mt) {
            f32x4 c = bias1[mt];
            c = __builtin_amdgcn_mfma_f32_16x16x32_bf16(w1f[mt], af[t], c, 0, 0, 0);
            // 4 consecutive hidden at fixed edge -> one b64 write
            *reinterpret_cast<short4v*>(hb + l15 * 72 + mt * 16 + q * 4) = pack4_relu(c);
        }
        short8 h0 = *reinterpret_cast<const short8*>(hb + l15 * 72 + q * 8);
        short8 h1 = *reinterpret_cast<const short8*>(hb + l15 * 72 + 32 + q * 8);

        // layer2: D2[edge][f], 2 f-tiles, K=64; C cols = f, rows = edge(pos)
        f32x4 r0 = {bias2a, bias2a, bias2a, bias2a};
        f32x4 r1 = {bias2b, bias2b, bias2b, bias2b};
        r0 = __builtin_amdgcn_mfma_f32_16x16x32_bf16(h0, w2f[0], r0, 0, 0, 0);
        r0 = __builtin_amdgcn_mfma_f32_16x16x32_bf16(h1, w2f[1], r0, 0, 0, 0);
        r1 = __builtin_amdgcn_mfma_f32_16x16x32_bf16(h0, w2f[2], r1, 0, 0, 0);
        r1 = __builtin_amdgcn_mfma_f32_16x16x32_bf16(h1, w2f[3], r1, 0, 0, 0);

        // relu + stage: 4 consecutive positions at fixed f -> one b128 write
        const int pb = w * 64 + t * 16 + q * 4;
        *reinterpret_cast<f32x4*>(red + l15 * RED_S + pb) =
            f32x4{fmaxf(r0[0], 0.f), fmaxf(r0[1], 0.f), fmaxf(r0[2], 0.f), fmaxf(r0[3], 0.f)};
        *reinterpret_cast<f32x4*>(red + (16 + l15) * RED_S + pb) =
            f32x4{fmaxf(r1[0], 0.f), fmaxf(r1[1], 0.f), fmaxf(r1[2], 0.f), fmaxf(r1[3], 0.f)};
    }
    __syncthreads();

    // segmented reduction: group g handles positions [32g, 32g+32), lane = feature
    const int g = tid >> 5;
    const int f = tid & 31;
    const int base = g * 32;

    f32x4 v4[8];
    #pragma unroll
    for (int i = 0; i < 8; ++i)
        v4[i] = *reinterpret_cast<const f32x4*>(red + f * RED_S + base + 4 * i);
    int4 r4[8];
    #pragma unroll
    for (int i = 0; i < 8; ++i)
        r4[i] = *reinterpret_cast<const int4*>(rs + base + 4 * i);

    const int first = r4[0].x;
    const int last  = r4[7].w;
    if (first == last) {
        // uniform chunk: straight sum, one atomic
        float acc = 0.f;
        #pragma unroll
        for (int i = 0; i < 8; ++i)
            acc += (v4[i][0] + v4[i][1]) + (v4[i][2] + v4[i][3]);
        atomicAdd(rel + ((size_t)b * N + first) * R + f, acc);
    } else {
        float acc = 0.f;
        int cur = first;
        #pragma unroll
        for (int i = 0; i < 32; ++i) {
            int rr = (i & 3) == 0 ? r4[i >> 2].x : (i & 3) == 1 ? r4[i >> 2].y
                   : (i & 3) == 2 ? r4[i >> 2].z : r4[i >> 2].w;
            float v = v4[i >> 2][i & 3];
            if (rr != cur) {
                atomicAdd(rel + ((size_t)b * N + cur) * R + f, acc);
                acc = 0.f;
                cur = rr;
            }
            acc += v;
        }
        atomicAdd(rel + ((size_t)b * N + cur) * R + f, acc);
    }
}

// ---------- MFMA node MLP: one 16-node tile per wave ----------
// Layer1: D[hidden][node] = W3^T(A) @ dyn_in^T(B), K=48 padded to 64
// Layer2: D[d][node] = W4^T(A) @ h^T(B) -> residual float4 store
__global__ __launch_bounds__(256, 4) void node_mfma_kernel(
    const float* __restrict__ particles,
    const float* __restrict__ rel,
    const short* __restrict__ w3p, const float* __restrict__ b3,
    const short* __restrict__ w4p, const float* __restrict__ b4,
    float* __restrict__ out)
{
    __shared__ short hbuf[4][16 * 72];

    const int tid  = threadIdx.x;
    const int lane = tid & 63;
    const int w    = tid >> 6;
    const int tile = blockIdx.x * 4 + w;        // [0, B*N/16)
    const int b    = tile >> 9;                 // 512 tiles per batch
    const int l15  = lane & 15;
    const int q    = lane >> 4;
    const int node = (tile & 511) * 16 + l15;

    const float* prow = particles + ((size_t)b * N + node) * D;
    const float* rrow = rel + ((size_t)b * N + node) * R;

    // B-frag chunk0: k=0..31 -> q0: p[0:8], q1: p[8:16], q2: rel[0:8], q3: rel[8:16]
    const float* src0 = (q < 2) ? (prow + (q & 1) * 8) : (rrow + (q & 1) * 8);
    float4 c0a = ld4(src0), c0b = ld4(src0 + 4);
    // chunk1: k=32..47 -> rel[16:32] (q<2), k>=48 zero
    float4 c1a = {0.f, 0.f, 0.f, 0.f}, c1b = {0.f, 0.f, 0.f, 0.f};
    if (q < 2) { c1a = ld4(rrow + 16 + q * 8); c1b = ld4(rrow + 20 + q * 8); }

    short8 w3f[8], w4f[2];
    #pragma unroll
    for (int i = 0; i < 8; ++i)
        w3f[i] = *reinterpret_cast<const short8*>(w3p + (i * 64 + lane) * 8);
    #pragma unroll
    for (int i = 0; i < 2; ++i)
        w4f[i] = *reinterpret_cast<const short8*>(w4p + (i * 64 + lane) * 8);

    // bias3: rows = hidden = mt*16 + q*4 + rg
    f32x4 bias3[4];
    #pragma unroll
    for (int mt = 0; mt < 4; ++mt) {
        float4 t4 = ld4(b3 + mt * 16 + q * 4);
        bias3[mt] = f32x4{t4.x, t4.y, t4.z, t4.w};
    }
    f32x4 bias4;
    { float4 t4 = ld4(b4 + q * 4); bias4 = f32x4{t4.x, t4.y, t4.z, t4.w}; }

    short8 a0 = pack8(c0a, c0b);
    short8 a1 = pack8(c1a, c1b);

    short* hb = &hbuf[w][0];
    #pragma unroll
    for (int mt = 0; mt < 4; ++mt) {
        f32x4 c = bias3[mt];
        c = __builtin_amdgcn_mfma_f32_16x16x32_bf16(w3f[mt * 2 + 0], a0, c, 0, 0, 0);
        c = __builtin_amdgcn_mfma_f32_16x16x32_bf16(w3f[mt * 2 + 1], a1, c, 0, 0, 0);
        *reinterpret_cast<short4v*>(hb + l15 * 72 + mt * 16 + q * 4) = pack4_relu(c);
    }
    short8 h0 = *reinterpret_cast<const short8*>(hb + l15 * 72 + q * 8);
    short8 h1 = *reinterpret_cast<const short8*>(hb + l15 * 72 + 32 + q * 8);

    f32x4 r = bias4;
    r = __builtin_amdgcn_mfma_f32_16x16x32_bf16(w4f[0], h0, r, 0, 0, 0);
    r = __builtin_amdgcn_mfma_f32_16x16x32_bf16(w4f[1], h1, r, 0, 0, 0);

    // residual + store: col = node, rows d = q*4..q*4+3 -> one float4
    float4 pv = ld4(prow + q * 4);
    float4* po = reinterpret_cast<float4*>(out + ((size_t)b * N + node) * D + q * 4);
    *po = float4{pv.x + r[0], pv.y + r[1], pv.z + r[2], pv.w + r[3]};
}

// ---------- fallback path (fp32, correctness backstop) ----------

__global__ __launch_bounds__(256, 2) void edge_atomic_kernel(
    const float* __restrict__ particles,
    const int*   __restrict__ senders,
    const int*   __restrict__ receivers,
    const float* __restrict__ W1, const float* __restrict__ b1,
    const float* __restrict__ W2, const float* __restrict__ b2,
    float* __restrict__ rel)
{
    const int idx = blockIdx.x * 256 + threadIdx.x;
    const int b = idx >> 18;
    const int e = idx & (E - 1);
    const int s = senders[e];
    const int r = receivers[e];

    float4 ein4[8];
    {
        const float4* ps = reinterpret_cast<const float4*>(particles + ((size_t)b * N + s) * D);
        const float4* pr = reinterpret_cast<const float4*>(particles + ((size_t)b * N + r) * D);
        #pragma unroll
        for (int qq = 0; qq < 4; ++qq) ein4[qq] = ps[qq];
        #pragma unroll
        for (int qq = 0; qq < 4; ++qq) ein4[4 + qq] = pr[qq];
    }
    float4 rf4[8];
    #pragma unroll
    for (int qq = 0; qq < 8; ++qq) rf4[qq] = ld4(b2 + 4 * qq);

    for (int j4 = 0; j4 < H / 4; ++j4) {
        float4 h = ld4(b1 + 4 * j4);
        const float* w1c = W1 + 4 * j4;
        #pragma unroll
        for (int kv = 0; kv < 8; ++kv) {
            const float4 ev = ein4[kv];
            h = fma4(ev.x, ld4(w1c + (4 * kv + 0) * H), h);
            h = fma4(ev.y, ld4(w1c + (4 * kv + 1) * H), h);
            h = fma4(ev.z, ld4(w1c + (4 * kv + 2) * H), h);
            h = fma4(ev.w, ld4(w1c + (4 * kv + 3) * H), h);
        }
        h = relu4(h);
        const float* w2r = W2 + (4 * j4) * R;
        #pragma unroll
        for (int qq = 0; qq < 4; ++qq) {
            const float hq = (qq == 0) ? h.x : (qq == 1) ? h.y : (qq == 2) ? h.z : h.w;
            #pragma unroll
            for (int r4 = 0; r4 < 8; ++r4)
                rf4[r4] = fma4(hq, ld4(w2r + qq * R + 4 * r4), rf4[r4]);
        }
    }
    float* dst = rel + ((size_t)b * N + r) * R;
    #pragma unroll
    for (int r4 = 0; r4 < 8; ++r4) {
        float4 v = relu4(rf4[r4]);
        atomicAdd(dst + 4 * r4 + 0, v.x);
        atomicAdd(dst + 4 * r4 + 1, v.y);
        atomicAdd(dst + 4 * r4 + 2, v.z);
        atomicAdd(dst + 4 * r4 + 3, v.w);
    }
}

__global__ __launch_bounds__(256, 2) void node_valu_kernel(
    const float* __restrict__ particles,
    const float* __restrict__ rel,
    const float* __restrict__ W3, const float* __restrict__ b3,
    const float* __restrict__ W4, const float* __restrict__ b4,
    float* __restrict__ out)
{
    const int idx = blockIdx.x * 256 + threadIdx.x;
    float4 in4[12];
    {
        const float4* pp = reinterpret_cast<const float4*>(particles + (size_t)idx * D);
        #pragma unroll
        for (int qq = 0; qq < 4; ++qq) in4[qq] = pp[qq];
        const float4* pr = reinterpret_cast<const float4*>(rel + (size_t)idx * R);
        #pragma unroll
        for (int qq = 0; qq < 8; ++qq) in4[4 + qq] = pr[qq];
    }
    float4 dl4[4];
    #pragma unroll
    for (int qq = 0; qq < 4; ++qq) dl4[qq] = ld4(b4 + 4 * qq);

    for (int j4 = 0; j4 < H / 4; ++j4) {
        float4 h = ld4(b3 + 4 * j4);
        const float* w3c = W3 + 4 * j4;
        #pragma unroll
        for (int kv = 0; kv < 12; ++kv) {
            const float4 ev = in4[kv];
            h = fma4(ev.x, ld4(w3c + (4 * kv + 0) * H), h);
            h = fma4(ev.y, ld4(w3c + (4 * kv + 1) * H), h);
            h = fma4(ev.z, ld4(w3c + (4 * kv + 2) * H), h);
            h = fma4(ev.w, ld4(w3c + (4 * kv + 3) * H), h);
        }
        h = relu4(h);
        const float* w4r = W4 + (4 * j4) * D;
        #pragma unroll
        for (int qq = 0; qq < 4; ++qq) {
            const float hq = (qq == 0) ? h.x : (qq == 1) ? h.y : (qq == 2) ? h.z : h.w;
            #pragma unroll
            for (int d4 = 0; d4 < 4; ++d4)
                dl4[d4] = fma4(hq, ld4(w4r + qq * D + 4 * d4), dl4[d4]);
        }
    }
    float4* po = reinterpret_cast<float4*>(out + (size_t)idx * D);
    #pragma unroll
    for (int qq = 0; qq < 4; ++qq) {
        float4 v = dl4[qq];
        float4 pv = in4[qq];
        po[qq] = float4{pv.x + v.x, pv.y + v.y, pv.z + v.z, pv.w + v.w};
    }
}

}  // namespace

extern "C" void kernel_launch(void* const* d_in, const int* in_sizes, int n_in,
                              void* d_out, int out_size, void* d_ws, size_t ws_size,
                              hipStream_t stream) {
    const float* particles = (const float*)d_in[0];
    const int*   senders   = (const int*)d_in[1];
    const int*   receivers = (const int*)d_in[2];
    const float* W1 = (const float*)d_in[3];
    const float* b1 = (const float*)d_in[4];
    const float* W2 = (const float*)d_in[5];
    const float* b2 = (const float*)d_in[6];
    const float* W3 = (const float*)d_in[7];
    const float* b3 = (const float*)d_in[8];
    const float* W4 = (const float*)d_in[9];
    const float* b4 = (const float*)d_in[10];
    float* out = (float*)d_out;

    // workspace layout (256-B aligned slices)
    char* ws = (char*)d_ws;
    size_t off = 0;
    auto take = [&](size_t bytes) -> char* {
        char* p = ws + off;
        off = (off + bytes + 255) & ~(size_t)255;
        return p;
    };
    int*   cnt     = (int*)  take((size_t)N * 4);
    int*   pos     = (int*)  take((size_t)N * 4);
    int2*  sr      = (int2*) take((size_t)E * 8);
    float* rel     = (float*)take((size_t)B * N * R * 4);
    short* w1p     = (short*)take((size_t)4 * 64 * 8 * 2);
    short* w2p     = (short*)take((size_t)4 * 64 * 8 * 2);
    short* w3p     = (short*)take((size_t)8 * 64 * 8 * 2);
    short* w4p     = (short*)take((size_t)2 * 64 * 8 * 2);
    const bool fast = (off <= ws_size);

    if (fast) {
        hipMemsetAsync(cnt, 0, (size_t)N * 4, stream);
        hist_prepack_kernel<<<1025 + 128, 256, 0, stream>>>(
            receivers, cnt, W1, W2, W3, W4, w1p, w2p, w3p, w4p, (float4*)rel);
        scan_kernel<<<1, 1024, 0, stream>>>(cnt, pos);
        scatter_kernel<<<E / 256, 256, 0, stream>>>(senders, receivers, pos, sr);
        edge_mfma_kernel<<<(B * E) / 256, 256, 0, stream>>>(
            particles, sr, w1p, b1, w2p, b2, rel);
        node_mfma_kernel<<<(B * N / 16) / 4, 256, 0, stream>>>(
            particles, rel, w3p, b3, w4p, b4, out);
    } else {
        float* rel0 = (float*)d_ws;
        hipMemsetAsync(rel0, 0, (size_t)B * N * R * 4, stream);
        edge_atomic_kernel<<<(B * E) / 256, 256, 0, stream>>>(
            particles, senders, receivers, W1, b1, W2, b2, rel0);
        node_valu_kernel<<<(B * N) / 256, 256, 0, stream>>>(
            particles, rel0, W3, b3, W4, b4, out);
    }
}